// Round 1
// baseline (15130.936 us; speedup 1.0000x reference)
//
#include <hip/hip_runtime.h>
#include <hip/hip_bf16.h>

#define HS 64
#define NH 16
#define DMODEL 1024
#define SEQ 1024
#define NB 4
#define NL 6
#define VOCAB 32000
#define EPS_LN 1e-5f

static constexpr int ROWS = NB * SEQ;  // 4096

// ---------------- embedding: x[b,t,:] = tok_emb[token] + pos_emb[t] ----------------
__global__ __launch_bounds__(256) void embed_kernel(
    const int* __restrict__ tokens, const float* __restrict__ tok_emb,
    const float* __restrict__ pos_emb, float* __restrict__ x) {
  int row = blockIdx.x;              // b*SEQ + t
  int t = row & (SEQ - 1);
  int tok = tokens[row];
  int d = threadIdx.x * 4;
  float4 te = *(const float4*)(tok_emb + (size_t)tok * DMODEL + d);
  float4 pe = *(const float4*)(pos_emb + (size_t)t * DMODEL + d);
  te.x += pe.x; te.y += pe.y; te.z += pe.z; te.w += pe.w;
  *(float4*)(x + (size_t)row * DMODEL + d) = te;
}

// ---------------- LayerNorm: one block per row ----------------
__global__ __launch_bounds__(256) void ln_kernel(
    const float* __restrict__ in, float* __restrict__ outp,
    const float* __restrict__ g, const float* __restrict__ b) {
  int row = blockIdx.x;
  int tid = threadIdx.x;
  const float* xr = in + (size_t)row * DMODEL;
  float4 v4 = *(const float4*)(xr + tid * 4);
  float s = v4.x + v4.y + v4.z + v4.w;
  float s2 = v4.x * v4.x + v4.y * v4.y + v4.z * v4.z + v4.w * v4.w;
#pragma unroll
  for (int off = 32; off > 0; off >>= 1) {
    s  += __shfl_down(s, off, 64);
    s2 += __shfl_down(s2, off, 64);
  }
  __shared__ float red[8];
  __shared__ float stats[2];
  int wv = tid >> 6, lane = tid & 63;
  if (lane == 0) { red[wv] = s; red[4 + wv] = s2; }
  __syncthreads();
  if (tid == 0) {
    float ts = red[0] + red[1] + red[2] + red[3];
    float ts2 = red[4] + red[5] + red[6] + red[7];
    float mu = ts * (1.0f / DMODEL);
    float var = ts2 * (1.0f / DMODEL) - mu * mu;
    stats[0] = mu;
    stats[1] = rsqrtf(var + EPS_LN);
  }
  __syncthreads();
  float mu = stats[0], rstd = stats[1];
  float4 g4 = *(const float4*)(g + tid * 4);
  float4 b4 = *(const float4*)(b + tid * 4);
  float4 o4;
  o4.x = (v4.x - mu) * rstd * g4.x + b4.x;
  o4.y = (v4.y - mu) * rstd * g4.y + b4.y;
  o4.z = (v4.z - mu) * rstd * g4.z + b4.z;
  o4.w = (v4.w - mu) * rstd * g4.w + b4.w;
  *(float4*)(outp + (size_t)row * DMODEL + tid * 4) = o4;
}

// ---------------- QKV projection: per-head GEMM, 64x64 tile, BK=16 ----------------
// q[b,h,t,s] = sum_d A[b*T+t,d] * W[h,d,s]
__global__ __launch_bounds__(256) void qkv_kernel(
    const float* __restrict__ A, const float* __restrict__ Wq,
    const float* __restrict__ Wk, const float* __restrict__ Wv,
    float* __restrict__ q, float* __restrict__ k, float* __restrict__ v) {
  __shared__ float As[16][65];
  __shared__ float Bq[16][64], Bk[16][64], Bv[16][64];
  int h = blockIdx.x;
  int m0 = blockIdx.y * 64;
  int tid = threadIdx.x;
  int r0 = (tid >> 4) * 4;
  int c0 = (tid & 15) * 4;
  const float* wqh = Wq + (size_t)h * DMODEL * HS;
  const float* wkh = Wk + (size_t)h * DMODEL * HS;
  const float* wvh = Wv + (size_t)h * DMODEL * HS;
  float aq[4][4] = {}, ak[4][4] = {}, av[4][4] = {};
  int arow = tid >> 2, acol = (tid & 3) * 4;
  int brow = tid >> 4, bcol = (tid & 15) * 4;
  for (int k0 = 0; k0 < DMODEL; k0 += 16) {
    float4 a4 = *(const float4*)(A + (size_t)(m0 + arow) * DMODEL + k0 + acol);
    As[acol + 0][arow] = a4.x; As[acol + 1][arow] = a4.y;
    As[acol + 2][arow] = a4.z; As[acol + 3][arow] = a4.w;
    size_t boff = (size_t)(k0 + brow) * HS + bcol;
    *(float4*)&Bq[brow][bcol] = *(const float4*)(wqh + boff);
    *(float4*)&Bk[brow][bcol] = *(const float4*)(wkh + boff);
    *(float4*)&Bv[brow][bcol] = *(const float4*)(wvh + boff);
    __syncthreads();
#pragma unroll
    for (int kk = 0; kk < 16; ++kk) {
      float ra[4];
#pragma unroll
      for (int i = 0; i < 4; ++i) ra[i] = As[kk][r0 + i];
      float4 rq = *(const float4*)&Bq[kk][c0];
      float4 rk = *(const float4*)&Bk[kk][c0];
      float4 rv = *(const float4*)&Bv[kk][c0];
#pragma unroll
      for (int i = 0; i < 4; ++i) {
        aq[i][0] += ra[i] * rq.x; aq[i][1] += ra[i] * rq.y;
        aq[i][2] += ra[i] * rq.z; aq[i][3] += ra[i] * rq.w;
        ak[i][0] += ra[i] * rk.x; ak[i][1] += ra[i] * rk.y;
        ak[i][2] += ra[i] * rk.z; ak[i][3] += ra[i] * rk.w;
        av[i][0] += ra[i] * rv.x; av[i][1] += ra[i] * rv.y;
        av[i][2] += ra[i] * rv.z; av[i][3] += ra[i] * rv.w;
      }
    }
    __syncthreads();
  }
#pragma unroll
  for (int i = 0; i < 4; ++i) {
    int m = m0 + r0 + i;
    int bb = m >> 10, t = m & (SEQ - 1);
    size_t off = ((((size_t)bb * NH + h) * SEQ) + t) * HS + c0;
    *(float4*)(q + off) = make_float4(aq[i][0], aq[i][1], aq[i][2], aq[i][3]);
    *(float4*)(k + off) = make_float4(ak[i][0], ak[i][1], ak[i][2], ak[i][3]);
    *(float4*)(v + off) = make_float4(av[i][0], av[i][1], av[i][2], av[i][3]);
  }
}

// ---------------- flash-style causal attention ----------------
// grid (NB*NH, SEQ/64); block 256. Each block: one (b,h), 64 query rows.
// thread: row r = tid>>2 (0..63), group cg = tid&3 (16 cols / 16 dims).
__global__ __launch_bounds__(256) void attn_kernel(
    const float* __restrict__ q, const float* __restrict__ k,
    const float* __restrict__ v, float* __restrict__ outp) {
  __shared__ float qs[64][65];
  __shared__ float kps[64][65];  // key tile, reused as P tile
  __shared__ float vs[64][64];
  int bh = blockIdx.x;
  int qt = blockIdx.y;
  int tid = threadIdx.x;
  int r = tid >> 2;
  int cg = tid & 3;
  const float* qb = q + (size_t)bh * SEQ * HS;
  const float* kb = k + (size_t)bh * SEQ * HS;
  const float* vb = v + (size_t)bh * SEQ * HS;

#pragma unroll
  for (int i = 0; i < 4; ++i) {
    int lin = tid + i * 256;
    int row = lin >> 4;
    int c4 = (lin & 15) * 4;
    float4 qv = *(const float4*)(qb + (size_t)(qt * 64 + row) * HS + c4);
    qs[row][c4 + 0] = qv.x; qs[row][c4 + 1] = qv.y;
    qs[row][c4 + 2] = qv.z; qs[row][c4 + 3] = qv.w;
  }

  float m = -1e30f, l = 0.f;
  float o[16];
#pragma unroll
  for (int i = 0; i < 16; ++i) o[i] = 0.f;

  int qidx = qt * 64 + r;
  for (int kt = 0; kt <= qt; ++kt) {
    __syncthreads();  // previous tile fully consumed (also covers qs for kt=0)
#pragma unroll
    for (int i = 0; i < 4; ++i) {
      int lin = tid + i * 256;
      int row = lin >> 4;
      int c4 = (lin & 15) * 4;
      float4 kv = *(const float4*)(kb + (size_t)(kt * 64 + row) * HS + c4);
      kps[row][c4 + 0] = kv.x; kps[row][c4 + 1] = kv.y;
      kps[row][c4 + 2] = kv.z; kps[row][c4 + 3] = kv.w;
      *(float4*)&vs[row][c4] = *(const float4*)(vb + (size_t)(kt * 64 + row) * HS + c4);
    }
    __syncthreads();
    float sc[16];
#pragma unroll
    for (int j = 0; j < 16; ++j) sc[j] = 0.f;
    for (int d = 0; d < 64; ++d) {
      float qv = qs[r][d];
#pragma unroll
      for (int j = 0; j < 16; ++j) sc[j] += qv * kps[cg * 16 + j][d];
    }
#pragma unroll
    for (int j = 0; j < 16; ++j) {
      int kidx = kt * 64 + cg * 16 + j;
      sc[j] = (kidx > qidx) ? -1e30f : sc[j] * 0.125f;
    }
    float mx = sc[0];
#pragma unroll
    for (int j = 1; j < 16; ++j) mx = fmaxf(mx, sc[j]);
    mx = fmaxf(mx, __shfl_xor(mx, 1, 64));
    mx = fmaxf(mx, __shfl_xor(mx, 2, 64));
    float m_new = fmaxf(m, mx);
    float scale = __expf(m - m_new);
    float psum = 0.f;
#pragma unroll
    for (int j = 0; j < 16; ++j) {
      sc[j] = __expf(sc[j] - m_new);
      psum += sc[j];
    }
    psum += __shfl_xor(psum, 1, 64);
    psum += __shfl_xor(psum, 2, 64);
    l = l * scale + psum;
    m = m_new;
#pragma unroll
    for (int i = 0; i < 16; ++i) o[i] *= scale;
    __syncthreads();  // done reading k-tile from kps
#pragma unroll
    for (int j = 0; j < 16; ++j) kps[r][cg * 16 + j] = sc[j];
    __syncthreads();
    for (int c = 0; c < 64; ++c) {
      float pval = kps[r][c];
#pragma unroll
      for (int dd = 0; dd < 16; ++dd) o[dd] += pval * vs[c][cg * 16 + dd];
    }
  }
  float inv_l = 1.0f / l;
  int bb = bh >> 4, hh = bh & 15;
  size_t base = ((size_t)bb * SEQ + (size_t)qidx) * DMODEL + hh * HS + cg * 16;
#pragma unroll
  for (int i = 0; i < 4; ++i) {
    *(float4*)(outp + base + i * 4) =
        make_float4(o[i * 4 + 0] * inv_l, o[i * 4 + 1] * inv_l,
                    o[i * 4 + 2] * inv_l, o[i * 4 + 3] * inv_l);
  }
}

// ---------------- generic GEMM: C = A[MxK] * B[KxN] + bias (+res) (+relu) ----------------
__global__ __launch_bounds__(256) void gemm_kernel(
    const float* __restrict__ A, const float* __restrict__ Bw,
    const float* __restrict__ bias, const float* __restrict__ res,
    float* __restrict__ C, int M, int N, int K, int relu) {
  __shared__ float As[16][65];  // transposed: As[k][m]
  __shared__ float Bs[16][64];
  int tid = threadIdx.x;
  int n0 = blockIdx.x * 64;
  int m0 = blockIdx.y * 64;
  int r0 = (tid >> 4) * 4;
  int c0 = (tid & 15) * 4;
  int arow = tid >> 2, acol = (tid & 3) * 4;
  int brow = tid >> 4, bcol = (tid & 15) * 4;
  float acc[4][4] = {};
  for (int k0 = 0; k0 < K; k0 += 16) {
    float4 a4 = *(const float4*)(A + (size_t)(m0 + arow) * K + k0 + acol);
    As[acol + 0][arow] = a4.x; As[acol + 1][arow] = a4.y;
    As[acol + 2][arow] = a4.z; As[acol + 3][arow] = a4.w;
    *(float4*)&Bs[brow][bcol] = *(const float4*)(Bw + (size_t)(k0 + brow) * N + n0 + bcol);
    __syncthreads();
#pragma unroll
    for (int kk = 0; kk < 16; ++kk) {
      float ra[4];
#pragma unroll
      for (int i = 0; i < 4; ++i) ra[i] = As[kk][r0 + i];
      float4 rb = *(const float4*)&Bs[kk][c0];
#pragma unroll
      for (int i = 0; i < 4; ++i) {
        acc[i][0] += ra[i] * rb.x; acc[i][1] += ra[i] * rb.y;
        acc[i][2] += ra[i] * rb.z; acc[i][3] += ra[i] * rb.w;
      }
    }
    __syncthreads();
  }
  float4 bv = *(const float4*)(bias + n0 + c0);
#pragma unroll
  for (int i = 0; i < 4; ++i) {
    int mrow = m0 + r0 + i;
    float4 o4;
    o4.x = acc[i][0] + bv.x; o4.y = acc[i][1] + bv.y;
    o4.z = acc[i][2] + bv.z; o4.w = acc[i][3] + bv.w;
    if (res) {
      float4 rv = *(const float4*)(res + (size_t)mrow * N + n0 + c0);
      o4.x += rv.x; o4.y += rv.y; o4.z += rv.z; o4.w += rv.w;
    }
    if (relu) {
      o4.x = fmaxf(o4.x, 0.f); o4.y = fmaxf(o4.y, 0.f);
      o4.z = fmaxf(o4.z, 0.f); o4.w = fmaxf(o4.w, 0.f);
    }
    *(float4*)(C + (size_t)mrow * N + n0 + c0) = o4;
  }
}

extern "C" void kernel_launch(void* const* d_in, const int* in_sizes, int n_in,
                              void* d_out, int out_size, void* d_ws, size_t ws_size,
                              hipStream_t stream) {
  const int*   tokens  = (const int*)d_in[0];
  const float* tok_emb = (const float*)d_in[1];
  const float* pos_emb = (const float*)d_in[2];
  const float* Wq      = (const float*)d_in[3];
  const float* Wk      = (const float*)d_in[4];
  const float* Wv      = (const float*)d_in[5];
  const float* Wo      = (const float*)d_in[6];
  const float* bo      = (const float*)d_in[7];
  const float* ln1_g   = (const float*)d_in[8];
  const float* ln1_b   = (const float*)d_in[9];
  const float* ln2_g   = (const float*)d_in[10];
  const float* ln2_b   = (const float*)d_in[11];
  const float* W1      = (const float*)d_in[12];
  const float* b1      = (const float*)d_in[13];
  const float* W2      = (const float*)d_in[14];
  const float* b2      = (const float*)d_in[15];
  const float* lnf_g   = (const float*)d_in[16];
  const float* lnf_b   = (const float*)d_in[17];
  const float* W_out   = (const float*)d_in[18];
  const float* b_out   = (const float*)d_in[19];
  float* logits = (float*)d_out;

  size_t SZ = (size_t)ROWS * DMODEL;  // 4M floats
  float* x   = (float*)d_ws;
  float* hb  = x + SZ;
  float* qb  = hb + SZ;
  float* kb  = qb + SZ;
  float* vb  = kb + SZ;
  float* att = vb + SZ;
  float* hid = att + SZ;  // 16M floats

  embed_kernel<<<ROWS, 256, 0, stream>>>(tokens, tok_emb, pos_emb, x);

  for (int l = 0; l < NL; ++l) {
    ln_kernel<<<ROWS, 256, 0, stream>>>(x, hb, ln1_g + l * DMODEL, ln1_b + l * DMODEL);
    qkv_kernel<<<dim3(NH, ROWS / 64), 256, 0, stream>>>(
        hb, Wq + (size_t)l * NH * DMODEL * HS, Wk + (size_t)l * NH * DMODEL * HS,
        Wv + (size_t)l * NH * DMODEL * HS, qb, kb, vb);
    attn_kernel<<<dim3(NB * NH, SEQ / 64), 256, 0, stream>>>(qb, kb, vb, att);
    gemm_kernel<<<dim3(DMODEL / 64, ROWS / 64), 256, 0, stream>>>(
        att, Wo + (size_t)l * DMODEL * DMODEL, bo + l * DMODEL, x, x,
        ROWS, DMODEL, DMODEL, 0);
    ln_kernel<<<ROWS, 256, 0, stream>>>(x, hb, ln2_g + l * DMODEL, ln2_b + l * DMODEL);
    gemm_kernel<<<dim3(4 * DMODEL / 64, ROWS / 64), 256, 0, stream>>>(
        hb, W1 + (size_t)l * DMODEL * 4 * DMODEL, b1 + (size_t)l * 4 * DMODEL, nullptr,
        hid, ROWS, 4 * DMODEL, DMODEL, 1);
    gemm_kernel<<<dim3(DMODEL / 64, ROWS / 64), 256, 0, stream>>>(
        hid, W2 + (size_t)l * 4 * DMODEL * DMODEL, b2 + l * DMODEL, x, x,
        ROWS, DMODEL, 4 * DMODEL, 0);
  }

  ln_kernel<<<ROWS, 256, 0, stream>>>(x, hb, lnf_g, lnf_b);
  gemm_kernel<<<dim3(VOCAB / 64, ROWS / 64), 256, 0, stream>>>(
      hb, W_out, b_out, nullptr, logits, ROWS, VOCAB, DMODEL, 0);
}

// Round 2
// 4327.473 us; speedup vs baseline: 3.4965x; 3.4965x over previous
//
#include <hip/hip_runtime.h>
#include <hip/hip_bf16.h>

#define HS 64
#define NH 16
#define DMODEL 1024
#define SEQ 1024
#define NB 4
#define NL 6
#define VOCAB 32000
#define EPS_LN 1e-5f

static constexpr int ROWS = NB * SEQ;  // 4096

typedef float f32x4 __attribute__((ext_vector_type(4)));
typedef short bf16x8 __attribute__((ext_vector_type(8)));
typedef unsigned short u16x8 __attribute__((ext_vector_type(8)));
typedef unsigned short u16x4 __attribute__((ext_vector_type(4)));

__device__ __forceinline__ unsigned short f2b(float f) {
  __hip_bfloat16 h = __float2bfloat16(f);
  return *reinterpret_cast<unsigned short*>(&h);
}
__device__ __forceinline__ float b2f(unsigned short u) {
  union { unsigned int i; float f; } v;
  v.i = ((unsigned int)u) << 16;
  return v.f;
}
__device__ __forceinline__ void gload_lds16(const void* g, void* l) {
  __builtin_amdgcn_global_load_lds(
      (const __attribute__((address_space(1))) void*)g,
      (__attribute__((address_space(3))) void*)l, 16, 0, 0);
}

// ---------------- embedding: x[b,t,:] = tok_emb[token] + pos_emb[t] (f32) ----------------
__global__ __launch_bounds__(256) void embed_kernel(
    const int* __restrict__ tokens, const float* __restrict__ tok_emb,
    const float* __restrict__ pos_emb, float* __restrict__ x) {
  int row = blockIdx.x;
  int t = row & (SEQ - 1);
  int tok = tokens[row];
  int d = threadIdx.x * 4;
  float4 te = *(const float4*)(tok_emb + (size_t)tok * DMODEL + d);
  float4 pe = *(const float4*)(pos_emb + (size_t)t * DMODEL + d);
  te.x += pe.x; te.y += pe.y; te.z += pe.z; te.w += pe.w;
  *(float4*)(x + (size_t)row * DMODEL + d) = te;
}

// ---------------- LayerNorm: f32 in -> bf16 out ----------------
__global__ __launch_bounds__(256) void ln_kernel(
    const float* __restrict__ in, unsigned short* __restrict__ outp,
    const float* __restrict__ g, const float* __restrict__ b) {
  int row = blockIdx.x;
  int tid = threadIdx.x;
  const float* xr = in + (size_t)row * DMODEL;
  float4 v4 = *(const float4*)(xr + tid * 4);
  float s = v4.x + v4.y + v4.z + v4.w;
  float s2 = v4.x * v4.x + v4.y * v4.y + v4.z * v4.z + v4.w * v4.w;
#pragma unroll
  for (int off = 32; off > 0; off >>= 1) {
    s  += __shfl_down(s, off, 64);
    s2 += __shfl_down(s2, off, 64);
  }
  __shared__ float red[8];
  __shared__ float stats[2];
  int wv = tid >> 6, lane = tid & 63;
  if (lane == 0) { red[wv] = s; red[4 + wv] = s2; }
  __syncthreads();
  if (tid == 0) {
    float ts = red[0] + red[1] + red[2] + red[3];
    float ts2 = red[4] + red[5] + red[6] + red[7];
    float mu = ts * (1.0f / DMODEL);
    float var = ts2 * (1.0f / DMODEL) - mu * mu;
    stats[0] = mu;
    stats[1] = rsqrtf(var + EPS_LN);
  }
  __syncthreads();
  float mu = stats[0], rstd = stats[1];
  float4 g4 = *(const float4*)(g + tid * 4);
  float4 b4 = *(const float4*)(b + tid * 4);
  u16x4 o;
  o[0] = f2b((v4.x - mu) * rstd * g4.x + b4.x);
  o[1] = f2b((v4.y - mu) * rstd * g4.y + b4.y);
  o[2] = f2b((v4.z - mu) * rstd * g4.z + b4.z);
  o[3] = f2b((v4.w - mu) * rstd * g4.w + b4.w);
  *(u16x4*)(outp + (size_t)row * DMODEL + tid * 4) = o;
}

// ---------------- transpose-convert: in f32 [K][N] -> out bf16 [N][K], z batches ----------------
__global__ __launch_bounds__(256) void transconv(
    const float* __restrict__ in, unsigned short* __restrict__ outp, int K, int N) {
  __shared__ float tile[32][33];
  size_t zoff = (size_t)blockIdx.z * K * N;
  in += zoff;
  outp += zoff;
  int n0 = blockIdx.x * 32, k0 = blockIdx.y * 32;
  int tx = threadIdx.x & 31, ty = threadIdx.x >> 5;
#pragma unroll
  for (int i = 0; i < 4; ++i)
    tile[ty + i * 8][tx] = in[(size_t)(k0 + ty + i * 8) * N + n0 + tx];
  __syncthreads();
#pragma unroll
  for (int i = 0; i < 4; ++i)
    outp[(size_t)(n0 + ty + i * 8) * K + k0 + tx] = f2b(tile[tx][ty + i * 8]);
}

// ---------------- QKV weight transpose-convert ----------------
// Wq/Wk/Wv: [L][H][D][HS] f32 -> qkvt[L][3072][1024] bf16 where row = which*1024 + h*64 + s
__global__ __launch_bounds__(256) void qkv_transconv(
    const float* __restrict__ Wq, const float* __restrict__ Wk,
    const float* __restrict__ Wv, unsigned short* __restrict__ outp) {
  __shared__ float tile[32][33];
  int z = blockIdx.z;            // l*48 + which*16 + h
  int l = z / 48;
  int r = z % 48;
  int which = r >> 4, h = r & 15;
  const float* W = (which == 0 ? Wq : which == 1 ? Wk : Wv) +
                   ((size_t)l * NH + h) * DMODEL * HS;
  int d0 = blockIdx.y * 32, s0 = blockIdx.x * 32;
  int tx = threadIdx.x & 31, ty = threadIdx.x >> 5;
#pragma unroll
  for (int i = 0; i < 4; ++i)
    tile[ty + i * 8][tx] = W[(size_t)(d0 + ty + i * 8) * HS + s0 + tx];
  __syncthreads();
  unsigned short* ob = outp + ((size_t)l * 3072 + which * 1024 + h * 64) * DMODEL;
#pragma unroll
  for (int i = 0; i < 4; ++i)
    ob[(size_t)(s0 + ty + i * 8) * DMODEL + d0 + tx] = f2b(tile[tx][ty + i * 8]);
}

// ---------------- bf16 MFMA GEMM: C[M][N] = A[M][K] * Bt[N][K]^T ----------------
// 128x128 tile, BK=32, 4 waves (each 64x64 = 4x4 frags of 16x16x32).
#define EPI_LOGITS 0
#define EPI_RES 1
#define EPI_RELU 2
#define EPI_QKV 3

template <int EPI>
__global__ __launch_bounds__(256) void mm128(
    const unsigned short* __restrict__ A, const unsigned short* __restrict__ Bt,
    const float* __restrict__ bias, const float* __restrict__ res,
    float* __restrict__ outf, unsigned short* __restrict__ ob0,
    unsigned short* __restrict__ ob1, unsigned short* __restrict__ ob2,
    int M, int N, int K) {
  __shared__ __align__(16) unsigned short As[128 * 32];
  __shared__ __align__(16) unsigned short Bs[128 * 32];
  int tid = threadIdx.x;
  int n0 = blockIdx.x * 128, m0 = blockIdx.y * 128;
  int lane = tid & 63, w = tid >> 6;
  int wm = (w >> 1) * 64, wn = (w & 1) * 64;

  // staging: thread t covers 16B (8 bf16); rows 0..63 (issue0), 64..127 (issue1)
  int srow = tid >> 2;
  int scol = (tid & 3) * 8;
  const unsigned short* aSrc0 = A + (size_t)(m0 + srow) * K + scol;
  const unsigned short* aSrc1 = A + (size_t)(m0 + srow + 64) * K + scol;
  const unsigned short* bSrc0 = Bt + (size_t)(n0 + srow) * K + scol;
  const unsigned short* bSrc1 = Bt + (size_t)(n0 + srow + 64) * K + scol;
  unsigned short* aDst0 = As + (size_t)tid * 8;
  unsigned short* aDst1 = As + (size_t)(tid + 256) * 8;
  unsigned short* bDst0 = Bs + (size_t)tid * 8;
  unsigned short* bDst1 = Bs + (size_t)(tid + 256) * 8;

  // compute-phase LDS pointers
  const unsigned short* PA = As + (size_t)(wm + (lane & 15)) * 32 + ((lane >> 4) * 8);
  const unsigned short* PB = Bs + (size_t)(wn + (lane & 15)) * 32 + ((lane >> 4) * 8);

  f32x4 acc[4][4] = {};
  for (int k0 = 0; k0 < K; k0 += 32) {
    gload_lds16(aSrc0 + k0, aDst0);
    gload_lds16(aSrc1 + k0, aDst1);
    gload_lds16(bSrc0 + k0, bDst0);
    gload_lds16(bSrc1 + k0, bDst1);
    __syncthreads();
    bf16x8 av[4], bv[4];
#pragma unroll
    for (int mi = 0; mi < 4; ++mi) av[mi] = *(const bf16x8*)(PA + mi * 512);
#pragma unroll
    for (int ni = 0; ni < 4; ++ni) bv[ni] = *(const bf16x8*)(PB + ni * 512);
#pragma unroll
    for (int mi = 0; mi < 4; ++mi)
#pragma unroll
      for (int ni = 0; ni < 4; ++ni)
        acc[mi][ni] = __builtin_amdgcn_mfma_f32_16x16x32_bf16(
            av[mi], bv[ni], acc[mi][ni], 0, 0, 0);
    __syncthreads();
  }

  // epilogue: C frag layout col = lane&15, row = (lane>>4)*4 + reg
  int rbase = m0 + wm + ((lane >> 4) << 2);
  int cbase = n0 + wn + (lane & 15);
#pragma unroll
  for (int ni = 0; ni < 4; ++ni) {
    int col = cbase + ni * 16;
    float bvv = 0.f;
    if (EPI != EPI_QKV) bvv = bias[col];
    if (EPI == EPI_QKV) {
      int which = col >> 10;
      int c2 = col & 1023;
      int h = c2 >> 6, s = c2 & 63;
      unsigned short* dst = which == 0 ? ob0 : which == 1 ? ob1 : ob2;
#pragma unroll
      for (int mi = 0; mi < 4; ++mi) {
        f32x4 a4 = acc[mi][ni];
#pragma unroll
        for (int r = 0; r < 4; ++r) {
          int rowg = rbase + mi * 16 + r;
          int bb = rowg >> 10, t = rowg & 1023;
          dst[((((size_t)bb * NH) + h) * SEQ + t) * HS + s] = f2b(a4[r]);
        }
      }
    } else {
#pragma unroll
      for (int mi = 0; mi < 4; ++mi) {
        f32x4 a4 = acc[mi][ni];
#pragma unroll
        for (int r = 0; r < 4; ++r) {
          int rowg = rbase + mi * 16 + r;
          size_t off = (size_t)rowg * N + col;
          float v = a4[r] + bvv;
          if (EPI == EPI_RES) outf[off] = v + res[off];
          else if (EPI == EPI_LOGITS) outf[off] = v;
          else if (EPI == EPI_RELU) ob0[off] = f2b(fmaxf(v, 0.f));
        }
      }
    }
  }
}

// ---------------- flash-style causal attention (bf16 in/out, f32 compute) ----------------
__global__ __launch_bounds__(256) void attn_kernel(
    const unsigned short* __restrict__ q, const unsigned short* __restrict__ k,
    const unsigned short* __restrict__ v, unsigned short* __restrict__ outp) {
  __shared__ float qs[64][65];
  __shared__ float kps[64][65];
  __shared__ float vs[64][64];
  int bh = blockIdx.x;
  int qt = blockIdx.y;
  int tid = threadIdx.x;
  int r = tid >> 2;
  int cg = tid & 3;
  const unsigned short* qb = q + (size_t)bh * SEQ * HS;
  const unsigned short* kb = k + (size_t)bh * SEQ * HS;
  const unsigned short* vb = v + (size_t)bh * SEQ * HS;

#pragma unroll
  for (int i = 0; i < 2; ++i) {
    int lin = tid + i * 256;
    int row = lin >> 3;
    int c8 = (lin & 7) * 8;
    u16x8 qv = *(const u16x8*)(qb + (size_t)(qt * 64 + row) * HS + c8);
#pragma unroll
    for (int j = 0; j < 8; ++j) qs[row][c8 + j] = b2f(qv[j]);
  }

  float m = -1e30f, l = 0.f;
  float o[16];
#pragma unroll
  for (int i = 0; i < 16; ++i) o[i] = 0.f;

  int qidx = qt * 64 + r;
  for (int kt = 0; kt <= qt; ++kt) {
    __syncthreads();
#pragma unroll
    for (int i = 0; i < 2; ++i) {
      int lin = tid + i * 256;
      int row = lin >> 3;
      int c8 = (lin & 7) * 8;
      u16x8 kv = *(const u16x8*)(kb + (size_t)(kt * 64 + row) * HS + c8);
      u16x8 vv = *(const u16x8*)(vb + (size_t)(kt * 64 + row) * HS + c8);
#pragma unroll
      for (int j = 0; j < 8; ++j) {
        kps[row][c8 + j] = b2f(kv[j]);
        vs[row][c8 + j] = b2f(vv[j]);
      }
    }
    __syncthreads();
    float sc[16];
#pragma unroll
    for (int j = 0; j < 16; ++j) sc[j] = 0.f;
    for (int d = 0; d < 64; ++d) {
      float qv = qs[r][d];
#pragma unroll
      for (int j = 0; j < 16; ++j) sc[j] += qv * kps[cg * 16 + j][d];
    }
#pragma unroll
    for (int j = 0; j < 16; ++j) {
      int kidx = kt * 64 + cg * 16 + j;
      sc[j] = (kidx > qidx) ? -1e30f : sc[j] * 0.125f;
    }
    float mx = sc[0];
#pragma unroll
    for (int j = 1; j < 16; ++j) mx = fmaxf(mx, sc[j]);
    mx = fmaxf(mx, __shfl_xor(mx, 1, 64));
    mx = fmaxf(mx, __shfl_xor(mx, 2, 64));
    float m_new = fmaxf(m, mx);
    float scale = __expf(m - m_new);
    float psum = 0.f;
#pragma unroll
    for (int j = 0; j < 16; ++j) {
      sc[j] = __expf(sc[j] - m_new);
      psum += sc[j];
    }
    psum += __shfl_xor(psum, 1, 64);
    psum += __shfl_xor(psum, 2, 64);
    l = l * scale + psum;
    m = m_new;
#pragma unroll
    for (int i = 0; i < 16; ++i) o[i] *= scale;
    __syncthreads();
#pragma unroll
    for (int j = 0; j < 16; ++j) kps[r][cg * 16 + j] = sc[j];
    __syncthreads();
    for (int c = 0; c < 64; ++c) {
      float pval = kps[r][c];
#pragma unroll
      for (int dd = 0; dd < 16; ++dd) o[dd] += pval * vs[c][cg * 16 + dd];
    }
  }
  float inv_l = 1.0f / l;
  int bb = bh >> 4, hh = bh & 15;
  size_t base = ((size_t)bb * SEQ + (size_t)qidx) * DMODEL + hh * HS + cg * 16;
#pragma unroll
  for (int i = 0; i < 2; ++i) {
    u16x8 o8;
#pragma unroll
    for (int j = 0; j < 8; ++j) o8[j] = f2b(o[i * 8 + j] * inv_l);
    *(u16x8*)(outp + base + i * 8) = o8;
  }
}

extern "C" void kernel_launch(void* const* d_in, const int* in_sizes, int n_in,
                              void* d_out, int out_size, void* d_ws, size_t ws_size,
                              hipStream_t stream) {
  const int*   tokens  = (const int*)d_in[0];
  const float* tok_emb = (const float*)d_in[1];
  const float* pos_emb = (const float*)d_in[2];
  const float* Wq      = (const float*)d_in[3];
  const float* Wk      = (const float*)d_in[4];
  const float* Wv      = (const float*)d_in[5];
  const float* Wo      = (const float*)d_in[6];
  const float* bo      = (const float*)d_in[7];
  const float* ln1_g   = (const float*)d_in[8];
  const float* ln1_b   = (const float*)d_in[9];
  const float* ln2_g   = (const float*)d_in[10];
  const float* ln2_b   = (const float*)d_in[11];
  const float* W1      = (const float*)d_in[12];
  const float* b1      = (const float*)d_in[13];
  const float* W2      = (const float*)d_in[14];
  const float* b2      = (const float*)d_in[15];
  const float* lnf_g   = (const float*)d_in[16];
  const float* lnf_b   = (const float*)d_in[17];
  const float* W_out   = (const float*)d_in[18];
  const float* b_out   = (const float*)d_in[19];
  float* logits = (float*)d_out;

  char* p = (char*)d_ws;
  float* x = (float*)p;            p += (size_t)ROWS * DMODEL * 4;       // 16 MB
  unsigned short* hb = (unsigned short*)p;  p += (size_t)ROWS * DMODEL * 2;   // 8 MB
  unsigned short* qb = (unsigned short*)p;  p += (size_t)ROWS * DMODEL * 2;
  unsigned short* kb = (unsigned short*)p;  p += (size_t)ROWS * DMODEL * 2;
  unsigned short* vb = (unsigned short*)p;  p += (size_t)ROWS * DMODEL * 2;
  unsigned short* att = (unsigned short*)p; p += (size_t)ROWS * DMODEL * 2;
  unsigned short* hid = (unsigned short*)p; p += (size_t)ROWS * 4 * DMODEL * 2;  // 32 MB
  unsigned short* qkvt = (unsigned short*)p; p += (size_t)NL * 3 * DMODEL * DMODEL * 2;
  unsigned short* wot = (unsigned short*)p;  p += (size_t)NL * DMODEL * DMODEL * 2;
  unsigned short* w1t = (unsigned short*)p;  p += (size_t)NL * 4 * DMODEL * DMODEL * 2;
  unsigned short* w2t = (unsigned short*)p;  p += (size_t)NL * 4 * DMODEL * DMODEL * 2;
  unsigned short* woutt = (unsigned short*)p; p += (size_t)VOCAB * DMODEL * 2;

  // weight conversion (per call; deterministic)
  transconv<<<dim3(32, 32, NL), 256, 0, stream>>>(Wo, wot, DMODEL, DMODEL);
  transconv<<<dim3(128, 32, NL), 256, 0, stream>>>(W1, w1t, DMODEL, 4 * DMODEL);
  transconv<<<dim3(32, 128, NL), 256, 0, stream>>>(W2, w2t, 4 * DMODEL, DMODEL);
  transconv<<<dim3(1000, 32, 1), 256, 0, stream>>>(W_out, woutt, DMODEL, VOCAB);
  qkv_transconv<<<dim3(2, 32, NL * 48), 256, 0, stream>>>(Wq, Wk, Wv, qkvt);

  embed_kernel<<<ROWS, 256, 0, stream>>>(tokens, tok_emb, pos_emb, x);

  for (int l = 0; l < NL; ++l) {
    ln_kernel<<<ROWS, 256, 0, stream>>>(x, hb, ln1_g + l * DMODEL, ln1_b + l * DMODEL);
    mm128<EPI_QKV><<<dim3(24, 32), 256, 0, stream>>>(
        hb, qkvt + (size_t)l * 3 * DMODEL * DMODEL, nullptr, nullptr,
        nullptr, qb, kb, vb, ROWS, 3 * DMODEL, DMODEL);
    attn_kernel<<<dim3(NB * NH, SEQ / 64), 256, 0, stream>>>(qb, kb, vb, att);
    mm128<EPI_RES><<<dim3(8, 32), 256, 0, stream>>>(
        att, wot + (size_t)l * DMODEL * DMODEL, bo + l * DMODEL, x,
        x, nullptr, nullptr, nullptr, ROWS, DMODEL, DMODEL);
    ln_kernel<<<ROWS, 256, 0, stream>>>(x, hb, ln2_g + l * DMODEL, ln2_b + l * DMODEL);
    mm128<EPI_RELU><<<dim3(32, 32), 256, 0, stream>>>(
        hb, w1t + (size_t)l * 4 * DMODEL * DMODEL, b1 + (size_t)l * 4 * DMODEL, nullptr,
        nullptr, hid, nullptr, nullptr, ROWS, 4 * DMODEL, DMODEL);
    mm128<EPI_RES><<<dim3(8, 32), 256, 0, stream>>>(
        hid, w2t + (size_t)l * 4 * DMODEL * DMODEL, b2 + l * DMODEL, x,
        x, nullptr, nullptr, nullptr, ROWS, DMODEL, 4 * DMODEL);
  }

  ln_kernel<<<ROWS, 256, 0, stream>>>(x, hb, lnf_g, lnf_b);
  mm128<EPI_LOGITS><<<dim3(VOCAB / 128, 32), 256, 0, stream>>>(
      hb, woutt, b_out, nullptr, logits, nullptr, nullptr, nullptr,
      ROWS, VOCAB, DMODEL);
}

// Round 3
// 2472.596 us; speedup vs baseline: 6.1195x; 1.7502x over previous
//
#include <hip/hip_runtime.h>
#include <hip/hip_bf16.h>

#define HS 64
#define NH 16
#define DMODEL 1024
#define SEQ 1024
#define NB 4
#define NL 6
#define VOCAB 32000
#define EPS_LN 1e-5f

static constexpr int ROWS = NB * SEQ;  // 4096

typedef float f32x4 __attribute__((ext_vector_type(4)));
typedef short bf16x8 __attribute__((ext_vector_type(8)));
typedef unsigned short u16x8 __attribute__((ext_vector_type(8)));
typedef unsigned short u16x4 __attribute__((ext_vector_type(4)));

__device__ __forceinline__ unsigned short f2b(float f) {
  __hip_bfloat16 h = __float2bfloat16(f);
  return *reinterpret_cast<unsigned short*>(&h);
}
__device__ __forceinline__ void gload_lds16(const void* g, void* l) {
  __builtin_amdgcn_global_load_lds(
      (const __attribute__((address_space(1))) void*)g,
      (__attribute__((address_space(3))) void*)l, 16, 0, 0);
}
#define MFMA16 __builtin_amdgcn_mfma_f32_16x16x32_bf16

// ---------------- embedding ----------------
__global__ __launch_bounds__(256) void embed_kernel(
    const int* __restrict__ tokens, const float* __restrict__ tok_emb,
    const float* __restrict__ pos_emb, float* __restrict__ x) {
  int row = blockIdx.x;
  int t = row & (SEQ - 1);
  int tok = tokens[row];
  int d = threadIdx.x * 4;
  float4 te = *(const float4*)(tok_emb + (size_t)tok * DMODEL + d);
  float4 pe = *(const float4*)(pos_emb + (size_t)t * DMODEL + d);
  te.x += pe.x; te.y += pe.y; te.z += pe.z; te.w += pe.w;
  *(float4*)(x + (size_t)row * DMODEL + d) = te;
}

// ---------------- LayerNorm: f32 in -> bf16 out ----------------
__global__ __launch_bounds__(256) void ln_kernel(
    const float* __restrict__ in, unsigned short* __restrict__ outp,
    const float* __restrict__ g, const float* __restrict__ b) {
  int row = blockIdx.x;
  int tid = threadIdx.x;
  const float* xr = in + (size_t)row * DMODEL;
  float4 v4 = *(const float4*)(xr + tid * 4);
  float s = v4.x + v4.y + v4.z + v4.w;
  float s2 = v4.x * v4.x + v4.y * v4.y + v4.z * v4.z + v4.w * v4.w;
#pragma unroll
  for (int off = 32; off > 0; off >>= 1) {
    s  += __shfl_down(s, off, 64);
    s2 += __shfl_down(s2, off, 64);
  }
  __shared__ float red[8];
  __shared__ float stats[2];
  int wv = tid >> 6, lane = tid & 63;
  if (lane == 0) { red[wv] = s; red[4 + wv] = s2; }
  __syncthreads();
  if (tid == 0) {
    float ts = red[0] + red[1] + red[2] + red[3];
    float ts2 = red[4] + red[5] + red[6] + red[7];
    float mu = ts * (1.0f / DMODEL);
    float var = ts2 * (1.0f / DMODEL) - mu * mu;
    stats[0] = mu;
    stats[1] = rsqrtf(var + EPS_LN);
  }
  __syncthreads();
  float mu = stats[0], rstd = stats[1];
  float4 g4 = *(const float4*)(g + tid * 4);
  float4 b4 = *(const float4*)(b + tid * 4);
  u16x4 o;
  o[0] = f2b((v4.x - mu) * rstd * g4.x + b4.x);
  o[1] = f2b((v4.y - mu) * rstd * g4.y + b4.y);
  o[2] = f2b((v4.z - mu) * rstd * g4.z + b4.z);
  o[3] = f2b((v4.w - mu) * rstd * g4.w + b4.w);
  *(u16x4*)(outp + (size_t)row * DMODEL + tid * 4) = o;
}

// ---------------- transpose-convert: f32 [K][N] -> bf16 [N][K] ----------------
__global__ __launch_bounds__(256) void transconv(
    const float* __restrict__ in, unsigned short* __restrict__ outp, int K, int N) {
  __shared__ float tile[32][33];
  size_t zoff = (size_t)blockIdx.z * K * N;
  in += zoff;
  outp += zoff;
  int n0 = blockIdx.x * 32, k0 = blockIdx.y * 32;
  int tx = threadIdx.x & 31, ty = threadIdx.x >> 5;
#pragma unroll
  for (int i = 0; i < 4; ++i)
    tile[ty + i * 8][tx] = in[(size_t)(k0 + ty + i * 8) * N + n0 + tx];
  __syncthreads();
#pragma unroll
  for (int i = 0; i < 4; ++i)
    outp[(size_t)(n0 + ty + i * 8) * K + k0 + tx] = f2b(tile[tx][ty + i * 8]);
}

// ---------------- QKV weight transpose-convert ----------------
__global__ __launch_bounds__(256) void qkv_transconv(
    const float* __restrict__ Wq, const float* __restrict__ Wk,
    const float* __restrict__ Wv, unsigned short* __restrict__ outp) {
  __shared__ float tile[32][33];
  int z = blockIdx.z;            // l*48 + which*16 + h
  int l = z / 48;
  int r = z % 48;
  int which = r >> 4, h = r & 15;
  const float* W = (which == 0 ? Wq : which == 1 ? Wk : Wv) +
                   ((size_t)l * NH + h) * DMODEL * HS;
  int d0 = blockIdx.y * 32, s0 = blockIdx.x * 32;
  int tx = threadIdx.x & 31, ty = threadIdx.x >> 5;
#pragma unroll
  for (int i = 0; i < 4; ++i)
    tile[ty + i * 8][tx] = W[(size_t)(d0 + ty + i * 8) * HS + s0 + tx];
  __syncthreads();
  unsigned short* ob = outp + ((size_t)l * 3072 + which * 1024 + h * 64) * DMODEL;
#pragma unroll
  for (int i = 0; i < 4; ++i)
    ob[(size_t)(s0 + ty + i * 8) * DMODEL + d0 + tx] = f2b(tile[tx][ty + i * 8]);
}

// ---------------- bf16 MFMA GEMM: C[M][N] = A[M][K] * Bt[N][K]^T ----------------
#define EPI_LOGITS 0
#define EPI_RES 1
#define EPI_RELU 2
#define EPI_QKV 3

template <int EPI, bool M_INNER>
__global__ __launch_bounds__(256) void mm128(
    const unsigned short* __restrict__ A, const unsigned short* __restrict__ Bt,
    const float* __restrict__ bias, const float* __restrict__ res,
    float* __restrict__ outf, unsigned short* __restrict__ ob0,
    unsigned short* __restrict__ ob1, unsigned short* __restrict__ ob2,
    int M, int N, int K) {
  __shared__ __align__(16) unsigned short As[128 * 32];
  __shared__ __align__(16) unsigned short Bs[128 * 32];
  int tid = threadIdx.x;
  // XCD-swizzled, weight-panel-inner linearization (nwg % 8 == 0 for all launches)
  int nM = M >> 7, nN = N >> 7;
  int nwg = nM * nN;
  int bid = blockIdx.y * gridDim.x + blockIdx.x;
  int wg = (bid & 7) * (nwg >> 3) + (bid >> 3);
  int mb, nb;
  if (M_INNER) { mb = wg % nM; nb = wg / nM; }
  else         { nb = wg % nN; mb = wg / nN; }
  int n0 = nb * 128, m0 = mb * 128;
  int lane = tid & 63, w = tid >> 6;
  int wm = (w >> 1) * 64, wn = (w & 1) * 64;

  int srow = tid >> 2;
  int scol = (tid & 3) * 8;
  const unsigned short* aSrc0 = A + (size_t)(m0 + srow) * K + scol;
  const unsigned short* aSrc1 = A + (size_t)(m0 + srow + 64) * K + scol;
  const unsigned short* bSrc0 = Bt + (size_t)(n0 + srow) * K + scol;
  const unsigned short* bSrc1 = Bt + (size_t)(n0 + srow + 64) * K + scol;
  unsigned short* aDst0 = As + (size_t)tid * 8;
  unsigned short* aDst1 = As + (size_t)(tid + 256) * 8;
  unsigned short* bDst0 = Bs + (size_t)tid * 8;
  unsigned short* bDst1 = Bs + (size_t)(tid + 256) * 8;

  const unsigned short* PA = As + (size_t)(wm + (lane & 15)) * 32 + ((lane >> 4) * 8);
  const unsigned short* PB = Bs + (size_t)(wn + (lane & 15)) * 32 + ((lane >> 4) * 8);

  f32x4 acc[4][4] = {};
  for (int k0 = 0; k0 < K; k0 += 32) {
    gload_lds16(aSrc0 + k0, aDst0);
    gload_lds16(aSrc1 + k0, aDst1);
    gload_lds16(bSrc0 + k0, bDst0);
    gload_lds16(bSrc1 + k0, bDst1);
    __syncthreads();
    bf16x8 av[4], bv[4];
#pragma unroll
    for (int mi = 0; mi < 4; ++mi) av[mi] = *(const bf16x8*)(PA + mi * 512);
#pragma unroll
    for (int ni = 0; ni < 4; ++ni) bv[ni] = *(const bf16x8*)(PB + ni * 512);
#pragma unroll
    for (int mi = 0; mi < 4; ++mi)
#pragma unroll
      for (int ni = 0; ni < 4; ++ni)
        acc[mi][ni] = MFMA16(av[mi], bv[ni], acc[mi][ni], 0, 0, 0);
    __syncthreads();
  }

  int rbase = m0 + wm + ((lane >> 4) << 2);
  int cbase = n0 + wn + (lane & 15);
#pragma unroll
  for (int ni = 0; ni < 4; ++ni) {
    int col = cbase + ni * 16;
    float bvv = 0.f;
    if (EPI != EPI_QKV) bvv = bias[col];
    if (EPI == EPI_QKV) {
      int which = col >> 10;
      int c2 = col & 1023;
      int h = c2 >> 6, s = c2 & 63;
#pragma unroll
      for (int mi = 0; mi < 4; ++mi) {
        f32x4 a4 = acc[mi][ni];
        int row0 = rbase + mi * 16;
        int bb = row0 >> 10, t0 = row0 & 1023;
        if (which == 2) {
          // V transposed: vt[((bb*NH+h)*HS + s)*SEQ + t], 4 consecutive t -> packed
          u16x4 p;
          p[0] = f2b(a4[0]); p[1] = f2b(a4[1]); p[2] = f2b(a4[2]); p[3] = f2b(a4[3]);
          *(u16x4*)(ob2 + ((((size_t)bb * NH + h) * HS) + s) * SEQ + t0) = p;
        } else {
          unsigned short* dst = (which == 0) ? ob0 : ob1;
#pragma unroll
          for (int r = 0; r < 4; ++r)
            dst[((((size_t)bb * NH) + h) * SEQ + t0 + r) * HS + s] = f2b(a4[r]);
        }
      }
    } else {
#pragma unroll
      for (int mi = 0; mi < 4; ++mi) {
        f32x4 a4 = acc[mi][ni];
#pragma unroll
        for (int r = 0; r < 4; ++r) {
          int rowg = rbase + mi * 16 + r;
          size_t off = (size_t)rowg * N + col;
          float v = a4[r] + bvv;
          if (EPI == EPI_RES) outf[off] = v + res[off];
          else if (EPI == EPI_LOGITS) outf[off] = v;
          else if (EPI == EPI_RELU) ob0[off] = f2b(fmaxf(v, 0.f));
        }
      }
    }
  }
}

// ---------------- MFMA flash attention (swapped-operand, causal) ----------------
// grid (qt=SEQ/64, bh=NB*NH), block 256 = 4 waves; wave w owns q rows w*16..w*16+15.
// S^T = mfma(K, Q): lane (l4,l15) holds S[key=16t+4*l4+r][q=w*16+l15] -> softmax in-lane.
// P redistributed via shfl to PV B-operand; O^T = mfma(V^T, P).
__global__ __launch_bounds__(256) void attn_mfma(
    const unsigned short* __restrict__ q, const unsigned short* __restrict__ k,
    const unsigned short* __restrict__ vt, unsigned short* __restrict__ outp) {
  __shared__ __align__(16) unsigned short S[8192];  // Ks[4096] | Vs[4096]; reused as Ol[64][72]
  unsigned short* Ks = S;
  unsigned short* Vs = S + 4096;
  int qt = blockIdx.x, bh = blockIdx.y;
  int tid = threadIdx.x;
  int lane = tid & 63, w = tid >> 6;
  int l15 = lane & 15, l4 = lane >> 4;

  const unsigned short* qb = q + (size_t)bh * SEQ * HS;
  const unsigned short* kb = k + (size_t)bh * SEQ * HS;
  const unsigned short* vb = vt + (size_t)bh * HS * SEQ;

  int q_l = w * 16 + l15;
  int q_g = qt * 64 + q_l;
  bf16x8 qf[2];
  qf[0] = *(const bf16x8*)(qb + (size_t)q_g * HS + l4 * 8);
  qf[1] = *(const bf16x8*)(qb + (size_t)q_g * HS + l4 * 8 + 32);

  // staging: idx -> row16 = idx&15, tc = idx>>4 (t = tc>>3, chunk = tc&7)
  int i0 = tid, i1 = tid + 256;
  int kOff0 = (i0 >> 7) * 16 * HS + (i0 & 15) * HS + ((i0 >> 4) & 7) * 8;
  int kOff1 = (i1 >> 7) * 16 * HS + (i1 & 15) * HS + ((i1 >> 4) & 7) * 8;
  int vOff0 = ((i0 >> 7) * 16 + (i0 & 15)) * SEQ + ((i0 >> 4) & 7) * 8;
  int vOff1 = ((i1 >> 7) * 16 + (i1 & 15)) * SEQ + ((i1 >> 4) & 7) * 8;

  f32x4 o[4] = {};
  float mrun = -1e30f, lrun = 0.f;
  int baseLane = 32 * (l4 & 1) + l15;
  bool hi_t = (l4 >> 1) != 0;

  for (int kt = 0; kt <= qt; ++kt) {
    __syncthreads();
    const unsigned short* ksrc = kb + (size_t)kt * 64 * HS;
    gload_lds16(ksrc + kOff0, Ks + (size_t)i0 * 8);
    gload_lds16(ksrc + kOff1, Ks + (size_t)i1 * 8);
    gload_lds16(vb + vOff0 + kt * 64, Vs + (size_t)i0 * 8);
    gload_lds16(vb + vOff1 + kt * 64, Vs + (size_t)i1 * 8);
    __syncthreads();

    // QK^T (swapped): s[t] covers keys 16t..16t+15 for q = own column
    f32x4 s[4];
#pragma unroll
    for (int t = 0; t < 4; ++t) {
      bf16x8 kf0 = *(const bf16x8*)(Ks + ((size_t)(t * 8 + l4) * 16 + l15) * 8);
      bf16x8 kf1 = *(const bf16x8*)(Ks + ((size_t)(t * 8 + l4 + 4) * 16 + l15) * 8);
      s[t] = (f32x4){0.f, 0.f, 0.f, 0.f};
      s[t] = MFMA16(kf0, qf[0], s[t], 0, 0, 0);
      s[t] = MFMA16(kf1, qf[1], s[t], 0, 0, 0);
    }

    bool diag = (kt == qt);
    int keybase = kt * 64 + 4 * l4;
    float mx = -1e30f;
#pragma unroll
    for (int t = 0; t < 4; ++t)
#pragma unroll
      for (int r = 0; r < 4; ++r) {
        float sv = s[t][r] * 0.125f;
        if (diag && (keybase + 16 * t + r) > q_g) sv = -1e30f;
        s[t][r] = sv;
        mx = fmaxf(mx, sv);
      }
    mx = fmaxf(mx, __shfl_xor(mx, 16, 64));
    mx = fmaxf(mx, __shfl_xor(mx, 32, 64));
    float mnew = fmaxf(mrun, mx);
    float sc = __expf(mrun - mnew);
    float ps = 0.f;
    float p[4][4];
#pragma unroll
    for (int t = 0; t < 4; ++t)
#pragma unroll
      for (int r = 0; r < 4; ++r) {
        float e = __expf(s[t][r] - mnew);
        p[t][r] = e;
        ps += e;
      }
    ps += __shfl_xor(ps, 16, 64);
    ps += __shfl_xor(ps, 32, 64);
    lrun = lrun * sc + ps;
    mrun = mnew;
#pragma unroll
    for (int t2 = 0; t2 < 4; ++t2)
#pragma unroll
      for (int r = 0; r < 4; ++r) o[t2][r] *= sc;

    // pack P pairs: pd[t][h] = bf16x2 of keys (16t + 4*l4 + 2h, +1) for own q
    int pd[4][2];
#pragma unroll
    for (int t = 0; t < 4; ++t)
#pragma unroll
      for (int h = 0; h < 2; ++h)
        pd[t][h] = (int)f2b(p[t][2 * h]) | ((int)f2b(p[t][2 * h + 1]) << 16);

    // PV: Y[kk] = P keys 32kk+8*l4+{0..7}; dword d from lane baseLane+16*(d>>1), pd[2kk+(l4>>1)][d&1]
#pragma unroll
    for (int kk = 0; kk < 2; ++kk) {
      int a0 = __shfl(pd[2 * kk][0], baseLane, 64);
      int b0 = __shfl(pd[2 * kk + 1][0], baseLane, 64);
      int a1 = __shfl(pd[2 * kk][1], baseLane, 64);
      int b1 = __shfl(pd[2 * kk + 1][1], baseLane, 64);
      int a2 = __shfl(pd[2 * kk][0], baseLane + 16, 64);
      int b2 = __shfl(pd[2 * kk + 1][0], baseLane + 16, 64);
      int a3 = __shfl(pd[2 * kk][1], baseLane + 16, 64);
      int b3 = __shfl(pd[2 * kk + 1][1], baseLane + 16, 64);
      union { int4 i4; bf16x8 v; } yu;
      yu.i4.x = hi_t ? b0 : a0;
      yu.i4.y = hi_t ? b1 : a1;
      yu.i4.z = hi_t ? b2 : a2;
      yu.i4.w = hi_t ? b3 : a3;
#pragma unroll
      for (int t2 = 0; t2 < 4; ++t2) {
        bf16x8 vf = *(const bf16x8*)(Vs + ((size_t)(t2 * 8 + l4 + 4 * kk) * 16 + l15) * 8);
        o[t2] = MFMA16(vf, yu.v, o[t2], 0, 0, 0);
      }
    }
  }

  // epilogue: O^T frag -> LDS [q][hs] (stride 72) -> coalesced global
  __syncthreads();
  float inv = 1.0f / lrun;
  unsigned short* Ol = S;
#pragma unroll
  for (int t2 = 0; t2 < 4; ++t2) {
    u16x4 p4;
#pragma unroll
    for (int r = 0; r < 4; ++r) p4[r] = f2b(o[t2][r] * inv);
    *(u16x4*)(Ol + (size_t)q_l * 72 + 16 * t2 + 4 * l4) = p4;
  }
  __syncthreads();
  int row = tid >> 2, hs0 = (tid & 3) * 16;
  int bidx = bh >> 4, h = bh & 15;
  size_t gbase = ((size_t)bidx * SEQ + qt * 64 + row) * DMODEL + h * HS + hs0;
  u16x8 r0 = *(const u16x8*)(Ol + (size_t)row * 72 + hs0);
  u16x8 r1 = *(const u16x8*)(Ol + (size_t)row * 72 + hs0 + 8);
  *(u16x8*)(outp + gbase) = r0;
  *(u16x8*)(outp + gbase + 8) = r1;
}

extern "C" void kernel_launch(void* const* d_in, const int* in_sizes, int n_in,
                              void* d_out, int out_size, void* d_ws, size_t ws_size,
                              hipStream_t stream) {
  const int*   tokens  = (const int*)d_in[0];
  const float* tok_emb = (const float*)d_in[1];
  const float* pos_emb = (const float*)d_in[2];
  const float* Wq      = (const float*)d_in[3];
  const float* Wk      = (const float*)d_in[4];
  const float* Wv      = (const float*)d_in[5];
  const float* Wo      = (const float*)d_in[6];
  const float* bo      = (const float*)d_in[7];
  const float* ln1_g   = (const float*)d_in[8];
  const float* ln1_b   = (const float*)d_in[9];
  const float* ln2_g   = (const float*)d_in[10];
  const float* ln2_b   = (const float*)d_in[11];
  const float* W1      = (const float*)d_in[12];
  const float* b1      = (const float*)d_in[13];
  const float* W2      = (const float*)d_in[14];
  const float* b2      = (const float*)d_in[15];
  const float* lnf_g   = (const float*)d_in[16];
  const float* lnf_b   = (const float*)d_in[17];
  const float* W_out   = (const float*)d_in[18];
  const float* b_out   = (const float*)d_in[19];
  float* logits = (float*)d_out;

  char* p = (char*)d_ws;
  float* x = (float*)p;            p += (size_t)ROWS * DMODEL * 4;
  unsigned short* hb = (unsigned short*)p;  p += (size_t)ROWS * DMODEL * 2;
  unsigned short* qb = (unsigned short*)p;  p += (size_t)ROWS * DMODEL * 2;
  unsigned short* kb = (unsigned short*)p;  p += (size_t)ROWS * DMODEL * 2;
  unsigned short* vtb = (unsigned short*)p; p += (size_t)ROWS * DMODEL * 2;
  unsigned short* att = (unsigned short*)p; p += (size_t)ROWS * DMODEL * 2;
  unsigned short* hid = (unsigned short*)p; p += (size_t)ROWS * 4 * DMODEL * 2;
  unsigned short* qkvt = (unsigned short*)p; p += (size_t)NL * 3 * DMODEL * DMODEL * 2;
  unsigned short* wot = (unsigned short*)p;  p += (size_t)NL * DMODEL * DMODEL * 2;
  unsigned short* w1t = (unsigned short*)p;  p += (size_t)NL * 4 * DMODEL * DMODEL * 2;
  unsigned short* w2t = (unsigned short*)p;  p += (size_t)NL * 4 * DMODEL * DMODEL * 2;
  unsigned short* woutt = (unsigned short*)p; p += (size_t)VOCAB * DMODEL * 2;

  transconv<<<dim3(32, 32, NL), 256, 0, stream>>>(Wo, wot, DMODEL, DMODEL);
  transconv<<<dim3(128, 32, NL), 256, 0, stream>>>(W1, w1t, DMODEL, 4 * DMODEL);
  transconv<<<dim3(32, 128, NL), 256, 0, stream>>>(W2, w2t, 4 * DMODEL, DMODEL);
  transconv<<<dim3(1000, 32, 1), 256, 0, stream>>>(W_out, woutt, DMODEL, VOCAB);
  qkv_transconv<<<dim3(2, 32, NL * 48), 256, 0, stream>>>(Wq, Wk, Wv, qkvt);

  embed_kernel<<<ROWS, 256, 0, stream>>>(tokens, tok_emb, pos_emb, x);

  for (int l = 0; l < NL; ++l) {
    ln_kernel<<<ROWS, 256, 0, stream>>>(x, hb, ln1_g + l * DMODEL, ln1_b + l * DMODEL);
    mm128<EPI_QKV, true><<<dim3(24, 32), 256, 0, stream>>>(
        hb, qkvt + (size_t)l * 3 * DMODEL * DMODEL, nullptr, nullptr,
        nullptr, qb, kb, vtb, ROWS, 3 * DMODEL, DMODEL);
    attn_mfma<<<dim3(SEQ / 64, NB * NH), 256, 0, stream>>>(qb, kb, vtb, att);
    mm128<EPI_RES, true><<<dim3(8, 32), 256, 0, stream>>>(
        att, wot + (size_t)l * DMODEL * DMODEL, bo + l * DMODEL, x,
        x, nullptr, nullptr, nullptr, ROWS, DMODEL, DMODEL);
    ln_kernel<<<ROWS, 256, 0, stream>>>(x, hb, ln2_g + l * DMODEL, ln2_b + l * DMODEL);
    mm128<EPI_RELU, true><<<dim3(32, 32), 256, 0, stream>>>(
        hb, w1t + (size_t)l * 4 * DMODEL * DMODEL, b1 + (size_t)l * 4 * DMODEL, nullptr,
        nullptr, hid, nullptr, nullptr, ROWS, 4 * DMODEL, DMODEL);
    mm128<EPI_RES, false><<<dim3(8, 32), 256, 0, stream>>>(
        hid, w2t + (size_t)l * 4 * DMODEL * DMODEL, b2 + l * DMODEL, x,
        x, nullptr, nullptr, nullptr, ROWS, DMODEL, 4 * DMODEL);
  }

  ln_kernel<<<ROWS, 256, 0, stream>>>(x, hb, lnf_g, lnf_b);
  mm128<EPI_LOGITS, true><<<dim3(VOCAB / 128, 32), 256, 0, stream>>>(
      hb, woutt, b_out, nullptr, logits, nullptr, nullptr, nullptr,
      ROWS, VOCAB, DMODEL);
}

// Round 5
// 2286.366 us; speedup vs baseline: 6.6179x; 1.0815x over previous
//
#include <hip/hip_runtime.h>
#include <hip/hip_bf16.h>

#define HS 64
#define NH 16
#define DMODEL 1024
#define SEQ 1024
#define NB 4
#define NL 6
#define VOCAB 32000
#define EPS_LN 1e-5f

static constexpr int ROWS = NB * SEQ;  // 4096

typedef float f32x4 __attribute__((ext_vector_type(4)));
typedef short bf16x8 __attribute__((ext_vector_type(8)));
typedef unsigned short u16x8 __attribute__((ext_vector_type(8)));
typedef unsigned short u16x4 __attribute__((ext_vector_type(4)));

__device__ __forceinline__ unsigned short f2b(float f) {
  __hip_bfloat16 h = __float2bfloat16(f);
  return *reinterpret_cast<unsigned short*>(&h);
}
__device__ __forceinline__ void gload_lds16(const void* g, void* l) {
  __builtin_amdgcn_global_load_lds(
      (const __attribute__((address_space(1))) void*)g,
      (__attribute__((address_space(3))) void*)l, 16, 0, 0);
}
#define MFMA16 __builtin_amdgcn_mfma_f32_16x16x32_bf16

// ---------------- embedding ----------------
__global__ __launch_bounds__(256) void embed_kernel(
    const int* __restrict__ tokens, const float* __restrict__ tok_emb,
    const float* __restrict__ pos_emb, float* __restrict__ x) {
  int row = blockIdx.x;
  int t = row & (SEQ - 1);
  int tok = tokens[row];
  int d = threadIdx.x * 4;
  float4 te = *(const float4*)(tok_emb + (size_t)tok * DMODEL + d);
  float4 pe = *(const float4*)(pos_emb + (size_t)t * DMODEL + d);
  te.x += pe.x; te.y += pe.y; te.z += pe.z; te.w += pe.w;
  *(float4*)(x + (size_t)row * DMODEL + d) = te;
}

// ---------------- LayerNorm: f32 in -> bf16 out ----------------
__global__ __launch_bounds__(256) void ln_kernel(
    const float* __restrict__ in, unsigned short* __restrict__ outp,
    const float* __restrict__ g, const float* __restrict__ b) {
  int row = blockIdx.x;
  int tid = threadIdx.x;
  const float* xr = in + (size_t)row * DMODEL;
  float4 v4 = *(const float4*)(xr + tid * 4);
  float s = v4.x + v4.y + v4.z + v4.w;
  float s2 = v4.x * v4.x + v4.y * v4.y + v4.z * v4.z + v4.w * v4.w;
#pragma unroll
  for (int off = 32; off > 0; off >>= 1) {
    s  += __shfl_down(s, off, 64);
    s2 += __shfl_down(s2, off, 64);
  }
  __shared__ float red[8];
  __shared__ float stats[2];
  int wv = tid >> 6, lane = tid & 63;
  if (lane == 0) { red[wv] = s; red[4 + wv] = s2; }
  __syncthreads();
  if (tid == 0) {
    float ts = red[0] + red[1] + red[2] + red[3];
    float ts2 = red[4] + red[5] + red[6] + red[7];
    float mu = ts * (1.0f / DMODEL);
    float var = ts2 * (1.0f / DMODEL) - mu * mu;
    stats[0] = mu;
    stats[1] = rsqrtf(var + EPS_LN);
  }
  __syncthreads();
  float mu = stats[0], rstd = stats[1];
  float4 g4 = *(const float4*)(g + tid * 4);
  float4 b4 = *(const float4*)(b + tid * 4);
  u16x4 o;
  o[0] = f2b((v4.x - mu) * rstd * g4.x + b4.x);
  o[1] = f2b((v4.y - mu) * rstd * g4.y + b4.y);
  o[2] = f2b((v4.z - mu) * rstd * g4.z + b4.z);
  o[3] = f2b((v4.w - mu) * rstd * g4.w + b4.w);
  *(u16x4*)(outp + (size_t)row * DMODEL + tid * 4) = o;
}

// ---------------- transpose-convert: f32 [K][N] -> bf16 [N][K] ----------------
__global__ __launch_bounds__(256) void transconv(
    const float* __restrict__ in, unsigned short* __restrict__ outp, int K, int N) {
  __shared__ float tile[32][33];
  size_t zoff = (size_t)blockIdx.z * K * N;
  in += zoff;
  outp += zoff;
  int n0 = blockIdx.x * 32, k0 = blockIdx.y * 32;
  int tx = threadIdx.x & 31, ty = threadIdx.x >> 5;
#pragma unroll
  for (int i = 0; i < 4; ++i)
    tile[ty + i * 8][tx] = in[(size_t)(k0 + ty + i * 8) * N + n0 + tx];
  __syncthreads();
#pragma unroll
  for (int i = 0; i < 4; ++i)
    outp[(size_t)(n0 + ty + i * 8) * K + k0 + tx] = f2b(tile[tx][ty + i * 8]);
}

// ---------------- QKV weight transpose-convert ----------------
__global__ __launch_bounds__(256) void qkv_transconv(
    const float* __restrict__ Wq, const float* __restrict__ Wk,
    const float* __restrict__ Wv, unsigned short* __restrict__ outp) {
  __shared__ float tile[32][33];
  int z = blockIdx.z;            // l*48 + which*16 + h
  int l = z / 48;
  int r = z % 48;
  int which = r >> 4, h = r & 15;
  const float* W = (which == 0 ? Wq : which == 1 ? Wk : Wv) +
                   ((size_t)l * NH + h) * DMODEL * HS;
  int d0 = blockIdx.y * 32, s0 = blockIdx.x * 32;
  int tx = threadIdx.x & 31, ty = threadIdx.x >> 5;
#pragma unroll
  for (int i = 0; i < 4; ++i)
    tile[ty + i * 8][tx] = W[(size_t)(d0 + ty + i * 8) * HS + s0 + tx];
  __syncthreads();
  unsigned short* ob = outp + ((size_t)l * 3072 + which * 1024 + h * 64) * DMODEL;
#pragma unroll
  for (int i = 0; i < 4; ++i)
    ob[(size_t)(s0 + ty + i * 8) * DMODEL + d0 + tx] = f2b(tile[tx][ty + i * 8]);
}

// ---------------- bf16 MFMA GEMM, 256x128 tile, BK=64, 3-deep pipeline ----------------
// C[M][N] = A[M][K] * Bt[N][K]^T.  512 threads = 8 waves (4M x 2N), each 64x64 out.
// LDS XOR-swizzle (T2): LDS(row, cb) holds global(row, cb ^ ((row&7)<<4)).
// Counted vmcnt (T4): tiles t+1,t+2 stay in flight across barriers.
#define EPI_LOGITS 0
#define EPI_RES 1
#define EPI_RELU 2
#define EPI_QKV 3

template <int EPI>
__global__ __launch_bounds__(512, 2) void mm256(
    const unsigned short* __restrict__ A, const unsigned short* __restrict__ Bt,
    const float* __restrict__ bias, const float* __restrict__ res,
    float* __restrict__ outf, unsigned short* __restrict__ ob0,
    unsigned short* __restrict__ ob1, unsigned short* __restrict__ ob2,
    int M, int N, int K) {
  __shared__ __align__(16) unsigned short As[3][256 * 64];
  __shared__ __align__(16) unsigned short Bs[3][128 * 64];
  const int tid = threadIdx.x;
  const int lane = tid & 63, w = tid >> 6;
  const int wm = (w >> 1) * 64;  // 4 m-waves
  const int wn = (w & 1) * 64;   // 2 n-waves

  // XCD-swizzled, weight-panel-inner linearization (nwg % 8 == 0 for all launches)
  const int nM = M >> 8, nN = N >> 7;
  const int nwg = nM * nN;
  int bid = blockIdx.x;
  int wg = (bid & 7) * (nwg >> 3) + (bid >> 3);
  int mb = wg % nM, nb = wg / nM;
  const int m0 = mb * 256, n0 = nb * 128;

  // staging: thread covers 16B; row_local = tid>>3, colbyte = (tid&7)*16.
  // source column pre-XORed so linear LDS dest yields swizzled layout (rule 21).
  const int srow = tid >> 3;
  const int scolb = (tid & 7) * 16;
  const int swst = (srow & 7) << 4;
  const char* aS = (const char*)A + ((size_t)(m0 + srow) * K) * 2 + (scolb ^ swst);
  const char* bS = (const char*)Bt + ((size_t)(n0 + srow) * K) * 2 + (scolb ^ swst);
  const size_t rstep = (size_t)64 * K * 2;  // 64 rows down

  // compute-side LDS addressing (rows of A/B tile, 128B per row)
  const int arow = wm + (lane & 15);
  const int brow = wn + (lane & 15);
  const int kb0 = (lane >> 4) * 16;
  const int swz = (lane & 7) << 4;  // (row&7)<<4, row&7 == lane&7

  const int NT = K >> 6;
  f32x4 acc[4][4] = {};

#define STAGE(tt)                                                      \
  {                                                                    \
    unsigned short* ad = &As[(tt) % 3][tid * 8];                       \
    unsigned short* bd = &Bs[(tt) % 3][tid * 8];                       \
    size_t ko = (size_t)(tt) * 128;                                    \
    gload_lds16(aS + ko, ad);                                          \
    gload_lds16(aS + ko + rstep, ad + 4096);                           \
    gload_lds16(aS + ko + 2 * rstep, ad + 8192);                       \
    gload_lds16(aS + ko + 3 * rstep, ad + 12288);                      \
    gload_lds16(bS + ko, bd);                                          \
    gload_lds16(bS + ko + rstep, bd + 4096);                           \
  }

  STAGE(0)
  STAGE(1)
  STAGE(2)

  for (int t = 0; t < NT; ++t) {
    int rem = NT - 1 - t;  // tiles already issued beyond t
    if (rem >= 2)      asm volatile("s_waitcnt vmcnt(12)" ::: "memory");
    else if (rem == 1) asm volatile("s_waitcnt vmcnt(6)" ::: "memory");
    else               asm volatile("s_waitcnt vmcnt(0)" ::: "memory");
    __builtin_amdgcn_s_barrier();
    __builtin_amdgcn_sched_barrier(0);
    const char* ab = (const char*)As[t % 3];
    const char* bb = (const char*)Bs[t % 3];
    bf16x8 av[4][2], bv[4][2];
#pragma unroll
    for (int mi = 0; mi < 4; ++mi)
#pragma unroll
      for (int ks = 0; ks < 2; ++ks) {
        // k-subtile ks starts at bf16 element 32*ks = byte 64*ks (was 32*ks: R4 bug)
        av[mi][ks] = *(const bf16x8*)(ab + (arow + 16 * mi) * 128 + ((kb0 + 64 * ks) ^ swz));
        bv[mi][ks] = *(const bf16x8*)(bb + (brow + 16 * mi) * 128 + ((kb0 + 64 * ks) ^ swz));
      }
    __builtin_amdgcn_sched_barrier(0);
    asm volatile("s_waitcnt lgkmcnt(0)" ::: "memory");
    __builtin_amdgcn_sched_barrier(0);
    __builtin_amdgcn_s_barrier();   // all waves done reading buf[t%3]
    __builtin_amdgcn_sched_barrier(0);
    if (t + 3 < NT) STAGE(t + 3)    // overwrite buf[t%3] with tile t+3
    __builtin_amdgcn_s_setprio(1);
#pragma unroll
    for (int ks = 0; ks < 2; ++ks)
#pragma unroll
      for (int mi = 0; mi < 4; ++mi)
#pragma unroll
        for (int ni = 0; ni < 4; ++ni)
          acc[mi][ni] = MFMA16(av[mi][ks], bv[ni][ks], acc[mi][ni], 0, 0, 0);
    __builtin_amdgcn_s_setprio(0);
  }
#undef STAGE

  // epilogue: C frag layout col = lane&15, row = (lane>>4)*4 + reg
  int rbase = m0 + wm + ((lane >> 4) << 2);
  int cbase = n0 + wn + (lane & 15);
#pragma unroll
  for (int ni = 0; ni < 4; ++ni) {
    int col = cbase + ni * 16;
    float bvv = 0.f;
    if (EPI != EPI_QKV) bvv = bias[col];
    if (EPI == EPI_QKV) {
      int which = col >> 10;
      int c2 = col & 1023;
      int h = c2 >> 6, s = c2 & 63;
#pragma unroll
      for (int mi = 0; mi < 4; ++mi) {
        f32x4 a4 = acc[mi][ni];
        int row0 = rbase + mi * 16;
        int bb2 = row0 >> 10, t0 = row0 & 1023;
        if (which == 2) {
          u16x4 pk;
          pk[0] = f2b(a4[0]); pk[1] = f2b(a4[1]); pk[2] = f2b(a4[2]); pk[3] = f2b(a4[3]);
          *(u16x4*)(ob2 + ((((size_t)bb2 * NH + h) * HS) + s) * SEQ + t0) = pk;
        } else {
          unsigned short* dst = (which == 0) ? ob0 : ob1;
#pragma unroll
          for (int r = 0; r < 4; ++r)
            dst[((((size_t)bb2 * NH) + h) * SEQ + t0 + r) * HS + s] = f2b(a4[r]);
        }
      }
    } else {
#pragma unroll
      for (int mi = 0; mi < 4; ++mi) {
        f32x4 a4 = acc[mi][ni];
#pragma unroll
        for (int r = 0; r < 4; ++r) {
          int rowg = rbase + mi * 16 + r;
          size_t off = (size_t)rowg * N + col;
          float v = a4[r] + bvv;
          if (EPI == EPI_RES) outf[off] = v + res[off];
          else if (EPI == EPI_LOGITS) outf[off] = v;
          else if (EPI == EPI_RELU) ob0[off] = f2b(fmaxf(v, 0.f));
        }
      }
    }
  }
}

// ---------------- MFMA flash attention (swapped-operand, causal) ----------------
__global__ __launch_bounds__(256) void attn_mfma(
    const unsigned short* __restrict__ q, const unsigned short* __restrict__ k,
    const unsigned short* __restrict__ vt, unsigned short* __restrict__ outp) {
  __shared__ __align__(16) unsigned short S[8192];  // Ks[4096] | Vs[4096]; reused as Ol
  unsigned short* Ks = S;
  unsigned short* Vs = S + 4096;
  int qt = blockIdx.x, bh = blockIdx.y;
  int tid = threadIdx.x;
  int lane = tid & 63, w = tid >> 6;
  int l15 = lane & 15, l4 = lane >> 4;

  const unsigned short* qb = q + (size_t)bh * SEQ * HS;
  const unsigned short* kb = k + (size_t)bh * SEQ * HS;
  const unsigned short* vb = vt + (size_t)bh * HS * SEQ;

  int q_l = w * 16 + l15;
  int q_g = qt * 64 + q_l;
  bf16x8 qf[2];
  qf[0] = *(const bf16x8*)(qb + (size_t)q_g * HS + l4 * 8);
  qf[1] = *(const bf16x8*)(qb + (size_t)q_g * HS + l4 * 8 + 32);

  int i0 = tid, i1 = tid + 256;
  int kOff0 = (i0 >> 7) * 16 * HS + (i0 & 15) * HS + ((i0 >> 4) & 7) * 8;
  int kOff1 = (i1 >> 7) * 16 * HS + (i1 & 15) * HS + ((i1 >> 4) & 7) * 8;
  int vOff0 = ((i0 >> 7) * 16 + (i0 & 15)) * SEQ + ((i0 >> 4) & 7) * 8;
  int vOff1 = ((i1 >> 7) * 16 + (i1 & 15)) * SEQ + ((i1 >> 4) & 7) * 8;

  f32x4 o[4] = {};
  float mrun = -1e30f, lrun = 0.f;
  int baseLane = 32 * (l4 & 1) + l15;
  bool hi_t = (l4 >> 1) != 0;

  for (int kt = 0; kt <= qt; ++kt) {
    __syncthreads();
    const unsigned short* ksrc = kb + (size_t)kt * 64 * HS;
    gload_lds16(ksrc + kOff0, Ks + (size_t)i0 * 8);
    gload_lds16(ksrc + kOff1, Ks + (size_t)i1 * 8);
    gload_lds16(vb + vOff0 + kt * 64, Vs + (size_t)i0 * 8);
    gload_lds16(vb + vOff1 + kt * 64, Vs + (size_t)i1 * 8);
    __syncthreads();

    f32x4 s[4];
#pragma unroll
    for (int t = 0; t < 4; ++t) {
      bf16x8 kf0 = *(const bf16x8*)(Ks + ((size_t)(t * 8 + l4) * 16 + l15) * 8);
      bf16x8 kf1 = *(const bf16x8*)(Ks + ((size_t)(t * 8 + l4 + 4) * 16 + l15) * 8);
      s[t] = (f32x4){0.f, 0.f, 0.f, 0.f};
      s[t] = MFMA16(kf0, qf[0], s[t], 0, 0, 0);
      s[t] = MFMA16(kf1, qf[1], s[t], 0, 0, 0);
    }

    bool diag = (kt == qt);
    int keybase = kt * 64 + 4 * l4;
    float mx = -1e30f;
#pragma unroll
    for (int t = 0; t < 4; ++t)
#pragma unroll
      for (int r = 0; r < 4; ++r) {
        float sv = s[t][r] * 0.125f;
        if (diag && (keybase + 16 * t + r) > q_g) sv = -1e30f;
        s[t][r] = sv;
        mx = fmaxf(mx, sv);
      }
    mx = fmaxf(mx, __shfl_xor(mx, 16, 64));
    mx = fmaxf(mx, __shfl_xor(mx, 32, 64));
    float mnew = fmaxf(mrun, mx);
    float sc = __expf(mrun - mnew);
    float ps = 0.f;
    float p[4][4];
#pragma unroll
    for (int t = 0; t < 4; ++t)
#pragma unroll
      for (int r = 0; r < 4; ++r) {
        float e = __expf(s[t][r] - mnew);
        p[t][r] = e;
        ps += e;
      }
    ps += __shfl_xor(ps, 16, 64);
    ps += __shfl_xor(ps, 32, 64);
    lrun = lrun * sc + ps;
    mrun = mnew;
#pragma unroll
    for (int t2 = 0; t2 < 4; ++t2)
#pragma unroll
      for (int r = 0; r < 4; ++r) o[t2][r] *= sc;

    int pd[4][2];
#pragma unroll
    for (int t = 0; t < 4; ++t)
#pragma unroll
      for (int h = 0; h < 2; ++h)
        pd[t][h] = (int)f2b(p[t][2 * h]) | ((int)f2b(p[t][2 * h + 1]) << 16);

#pragma unroll
    for (int kk = 0; kk < 2; ++kk) {
      int a0 = __shfl(pd[2 * kk][0], baseLane, 64);
      int b0 = __shfl(pd[2 * kk + 1][0], baseLane, 64);
      int a1 = __shfl(pd[2 * kk][1], baseLane, 64);
      int b1 = __shfl(pd[2 * kk + 1][1], baseLane, 64);
      int a2 = __shfl(pd[2 * kk][0], baseLane + 16, 64);
      int b2 = __shfl(pd[2 * kk + 1][0], baseLane + 16, 64);
      int a3 = __shfl(pd[2 * kk][1], baseLane + 16, 64);
      int b3 = __shfl(pd[2 * kk + 1][1], baseLane + 16, 64);
      union { int4 i4; bf16x8 v; } yu;
      yu.i4.x = hi_t ? b0 : a0;
      yu.i4.y = hi_t ? b1 : a1;
      yu.i4.z = hi_t ? b2 : a2;
      yu.i4.w = hi_t ? b3 : a3;
#pragma unroll
      for (int t2 = 0; t2 < 4; ++t2) {
        bf16x8 vf = *(const bf16x8*)(Vs + ((size_t)(t2 * 8 + l4 + 4 * kk) * 16 + l15) * 8);
        o[t2] = MFMA16(vf, yu.v, o[t2], 0, 0, 0);
      }
    }
  }

  __syncthreads();
  float inv = 1.0f / lrun;
  unsigned short* Ol = S;
#pragma unroll
  for (int t2 = 0; t2 < 4; ++t2) {
    u16x4 p4;
#pragma unroll
    for (int r = 0; r < 4; ++r) p4[r] = f2b(o[t2][r] * inv);
    *(u16x4*)(Ol + (size_t)q_l * 72 + 16 * t2 + 4 * l4) = p4;
  }
  __syncthreads();
  int row = tid >> 2, hs0 = (tid & 3) * 16;
  int bidx = bh >> 4, h = bh & 15;
  size_t gbase = ((size_t)bidx * SEQ + qt * 64 + row) * DMODEL + h * HS + hs0;
  u16x8 r0 = *(const u16x8*)(Ol + (size_t)row * 72 + hs0);
  u16x8 r1 = *(const u16x8*)(Ol + (size_t)row * 72 + hs0 + 8);
  *(u16x8*)(outp + gbase) = r0;
  *(u16x8*)(outp + gbase + 8) = r1;
}

extern "C" void kernel_launch(void* const* d_in, const int* in_sizes, int n_in,
                              void* d_out, int out_size, void* d_ws, size_t ws_size,
                              hipStream_t stream) {
  const int*   tokens  = (const int*)d_in[0];
  const float* tok_emb = (const float*)d_in[1];
  const float* pos_emb = (const float*)d_in[2];
  const float* Wq      = (const float*)d_in[3];
  const float* Wk      = (const float*)d_in[4];
  const float* Wv      = (const float*)d_in[5];
  const float* Wo      = (const float*)d_in[6];
  const float* bo      = (const float*)d_in[7];
  const float* ln1_g   = (const float*)d_in[8];
  const float* ln1_b   = (const float*)d_in[9];
  const float* ln2_g   = (const float*)d_in[10];
  const float* ln2_b   = (const float*)d_in[11];
  const float* W1      = (const float*)d_in[12];
  const float* b1      = (const float*)d_in[13];
  const float* W2      = (const float*)d_in[14];
  const float* b2      = (const float*)d_in[15];
  const float* lnf_g   = (const float*)d_in[16];
  const float* lnf_b   = (const float*)d_in[17];
  const float* W_out   = (const float*)d_in[18];
  const float* b_out   = (const float*)d_in[19];
  float* logits = (float*)d_out;

  char* p = (char*)d_ws;
  float* x = (float*)p;            p += (size_t)ROWS * DMODEL * 4;
  unsigned short* hb = (unsigned short*)p;  p += (size_t)ROWS * DMODEL * 2;
  unsigned short* qb = (unsigned short*)p;  p += (size_t)ROWS * DMODEL * 2;
  unsigned short* kb = (unsigned short*)p;  p += (size_t)ROWS * DMODEL * 2;
  unsigned short* vtb = (unsigned short*)p; p += (size_t)ROWS * DMODEL * 2;
  unsigned short* att = (unsigned short*)p; p += (size_t)ROWS * DMODEL * 2;
  unsigned short* hid = (unsigned short*)p; p += (size_t)ROWS * 4 * DMODEL * 2;
  unsigned short* qkvt = (unsigned short*)p; p += (size_t)NL * 3 * DMODEL * DMODEL * 2;
  unsigned short* wot = (unsigned short*)p;  p += (size_t)NL * DMODEL * DMODEL * 2;
  unsigned short* w1t = (unsigned short*)p;  p += (size_t)NL * 4 * DMODEL * DMODEL * 2;
  unsigned short* w2t = (unsigned short*)p;  p += (size_t)NL * 4 * DMODEL * DMODEL * 2;
  unsigned short* woutt = (unsigned short*)p; p += (size_t)VOCAB * DMODEL * 2;

  transconv<<<dim3(32, 32, NL), 256, 0, stream>>>(Wo, wot, DMODEL, DMODEL);
  transconv<<<dim3(128, 32, NL), 256, 0, stream>>>(W1, w1t, DMODEL, 4 * DMODEL);
  transconv<<<dim3(32, 128, NL), 256, 0, stream>>>(W2, w2t, 4 * DMODEL, DMODEL);
  transconv<<<dim3(1000, 32, 1), 256, 0, stream>>>(W_out, woutt, DMODEL, VOCAB);
  qkv_transconv<<<dim3(2, 32, NL * 48), 256, 0, stream>>>(Wq, Wk, Wv, qkvt);

  embed_kernel<<<ROWS, 256, 0, stream>>>(tokens, tok_emb, pos_emb, x);

  for (int l = 0; l < NL; ++l) {
    ln_kernel<<<ROWS, 256, 0, stream>>>(x, hb, ln1_g + l * DMODEL, ln1_b + l * DMODEL);
    mm256<EPI_QKV><<<16 * 24, 512, 0, stream>>>(
        hb, qkvt + (size_t)l * 3 * DMODEL * DMODEL, nullptr, nullptr,
        nullptr, qb, kb, vtb, ROWS, 3 * DMODEL, DMODEL);
    attn_mfma<<<dim3(SEQ / 64, NB * NH), 256, 0, stream>>>(qb, kb, vtb, att);
    mm256<EPI_RES><<<16 * 8, 512, 0, stream>>>(
        att, wot + (size_t)l * DMODEL * DMODEL, bo + l * DMODEL, x,
        x, nullptr, nullptr, nullptr, ROWS, DMODEL, DMODEL);
    ln_kernel<<<ROWS, 256, 0, stream>>>(x, hb, ln2_g + l * DMODEL, ln2_b + l * DMODEL);
    mm256<EPI_RELU><<<16 * 32, 512, 0, stream>>>(
        hb, w1t + (size_t)l * 4 * DMODEL * DMODEL, b1 + (size_t)l * 4 * DMODEL, nullptr,
        nullptr, hid, nullptr, nullptr, ROWS, 4 * DMODEL, DMODEL);
    mm256<EPI_RES><<<16 * 8, 512, 0, stream>>>(
        hid, w2t + (size_t)l * 4 * DMODEL * DMODEL, b2 + l * DMODEL, x,
        x, nullptr, nullptr, nullptr, ROWS, DMODEL, 4 * DMODEL);
  }

  ln_kernel<<<ROWS, 256, 0, stream>>>(x, hb, lnf_g, lnf_b);
  mm256<EPI_LOGITS><<<16 * 250, 512, 0, stream>>>(
      hb, woutt, b_out, nullptr, logits, nullptr, nullptr, nullptr,
      ROWS, VOCAB, DMODEL);
}

// Round 6
// 1942.147 us; speedup vs baseline: 7.7908x; 1.1772x over previous
//
#include <hip/hip_runtime.h>
#include <hip/hip_bf16.h>

#define HS 64
#define NH 16
#define DMODEL 1024
#define SEQ 1024
#define NB 4
#define NL 6
#define VOCAB 32000
#define EPS_LN 1e-5f

static constexpr int ROWS = NB * SEQ;  // 4096

typedef float f32x4 __attribute__((ext_vector_type(4)));
typedef short bf16x8 __attribute__((ext_vector_type(8)));
typedef unsigned short u16x8 __attribute__((ext_vector_type(8)));
typedef unsigned short u16x4 __attribute__((ext_vector_type(4)));

__device__ __forceinline__ unsigned short f2b(float f) {
  __hip_bfloat16 h = __float2bfloat16(f);
  return *reinterpret_cast<unsigned short*>(&h);
}
__device__ __forceinline__ void gload_lds16(const void* g, void* l) {
  __builtin_amdgcn_global_load_lds(
      (const __attribute__((address_space(1))) void*)g,
      (__attribute__((address_space(3))) void*)l, 16, 0, 0);
}
#define MFMA16 __builtin_amdgcn_mfma_f32_16x16x32_bf16

// ---------------- embedding ----------------
__global__ __launch_bounds__(256) void embed_kernel(
    const int* __restrict__ tokens, const float* __restrict__ tok_emb,
    const float* __restrict__ pos_emb, float* __restrict__ x) {
  int row = blockIdx.x;
  int t = row & (SEQ - 1);
  int tok = tokens[row];
  int d = threadIdx.x * 4;
  float4 te = *(const float4*)(tok_emb + (size_t)tok * DMODEL + d);
  float4 pe = *(const float4*)(pos_emb + (size_t)t * DMODEL + d);
  te.x += pe.x; te.y += pe.y; te.z += pe.z; te.w += pe.w;
  *(float4*)(x + (size_t)row * DMODEL + d) = te;
}

// ---------------- LayerNorm: f32 in -> bf16 out ----------------
__global__ __launch_bounds__(256) void ln_kernel(
    const float* __restrict__ in, unsigned short* __restrict__ outp,
    const float* __restrict__ g, const float* __restrict__ b) {
  int row = blockIdx.x;
  int tid = threadIdx.x;
  const float* xr = in + (size_t)row * DMODEL;
  float4 v4 = *(const float4*)(xr + tid * 4);
  float s = v4.x + v4.y + v4.z + v4.w;
  float s2 = v4.x * v4.x + v4.y * v4.y + v4.z * v4.z + v4.w * v4.w;
#pragma unroll
  for (int off = 32; off > 0; off >>= 1) {
    s  += __shfl_down(s, off, 64);
    s2 += __shfl_down(s2, off, 64);
  }
  __shared__ float red[8];
  __shared__ float stats[2];
  int wv = tid >> 6, lane = tid & 63;
  if (lane == 0) { red[wv] = s; red[4 + wv] = s2; }
  __syncthreads();
  if (tid == 0) {
    float ts = red[0] + red[1] + red[2] + red[3];
    float ts2 = red[4] + red[5] + red[6] + red[7];
    float mu = ts * (1.0f / DMODEL);
    float var = ts2 * (1.0f / DMODEL) - mu * mu;
    stats[0] = mu;
    stats[1] = rsqrtf(var + EPS_LN);
  }
  __syncthreads();
  float mu = stats[0], rstd = stats[1];
  float4 g4 = *(const float4*)(g + tid * 4);
  float4 b4 = *(const float4*)(b + tid * 4);
  u16x4 o;
  o[0] = f2b((v4.x - mu) * rstd * g4.x + b4.x);
  o[1] = f2b((v4.y - mu) * rstd * g4.y + b4.y);
  o[2] = f2b((v4.z - mu) * rstd * g4.z + b4.z);
  o[3] = f2b((v4.w - mu) * rstd * g4.w + b4.w);
  *(u16x4*)(outp + (size_t)row * DMODEL + tid * 4) = o;
}

// ---------------- transpose-convert: f32 [K][N] -> bf16 [N][K] ----------------
__global__ __launch_bounds__(256) void transconv(
    const float* __restrict__ in, unsigned short* __restrict__ outp, int K, int N) {
  __shared__ float tile[32][33];
  size_t zoff = (size_t)blockIdx.z * K * N;
  in += zoff;
  outp += zoff;
  int n0 = blockIdx.x * 32, k0 = blockIdx.y * 32;
  int tx = threadIdx.x & 31, ty = threadIdx.x >> 5;
#pragma unroll
  for (int i = 0; i < 4; ++i)
    tile[ty + i * 8][tx] = in[(size_t)(k0 + ty + i * 8) * N + n0 + tx];
  __syncthreads();
#pragma unroll
  for (int i = 0; i < 4; ++i)
    outp[(size_t)(n0 + ty + i * 8) * K + k0 + tx] = f2b(tile[tx][ty + i * 8]);
}

// ---------------- QKV weight transpose-convert ----------------
__global__ __launch_bounds__(256) void qkv_transconv(
    const float* __restrict__ Wq, const float* __restrict__ Wk,
    const float* __restrict__ Wv, unsigned short* __restrict__ outp) {
  __shared__ float tile[32][33];
  int z = blockIdx.z;            // l*48 + which*16 + h
  int l = z / 48;
  int r = z % 48;
  int which = r >> 4, h = r & 15;
  const float* W = (which == 0 ? Wq : which == 1 ? Wk : Wv) +
                   ((size_t)l * NH + h) * DMODEL * HS;
  int d0 = blockIdx.y * 32, s0 = blockIdx.x * 32;
  int tx = threadIdx.x & 31, ty = threadIdx.x >> 5;
#pragma unroll
  for (int i = 0; i < 4; ++i)
    tile[ty + i * 8][tx] = W[(size_t)(d0 + ty + i * 8) * HS + s0 + tx];
  __syncthreads();
  unsigned short* ob = outp + ((size_t)l * 3072 + which * 1024 + h * 64) * DMODEL;
#pragma unroll
  for (int i = 0; i < 4; ++i)
    ob[(size_t)(s0 + ty + i * 8) * DMODEL + d0 + tx] = f2b(tile[tx][ty + i * 8]);
}

// ---------------- bf16 MFMA GEMM, BM_ x 256 tile, BK=64, phase-pipelined ----------------
// C[M][N] = A[M][K] * Bt[N][K]^T. 512 threads = 8 waves (2M x 4N), wave = (BM_/2) x 64 out.
// 2-buffer ring, counted vmcnt gate; per K-tile 4 phases: ds_read(next m-group)
// overlaps MFMA(current m-group); only last phase drains lgkm + barrier.
#define EPI_LOGITS 0
#define EPI_RES 1
#define EPI_RELU 2
#define EPI_QKV 3

template <int EPI, int BM_>
__global__ __launch_bounds__(512, 2) void mmX(
    const unsigned short* __restrict__ A, const unsigned short* __restrict__ Bt,
    const float* __restrict__ bias, const float* __restrict__ res,
    float* __restrict__ outf, unsigned short* __restrict__ ob0,
    unsigned short* __restrict__ ob1, unsigned short* __restrict__ ob2,
    int M, int N, int K) {
  constexpr int NA = BM_ / 64;     // A gload issues per tile per thread
  constexpr int AP = BM_ / 128;    // m-frags per phase (2 or 1)
  constexpr int MFRAG = BM_ / 32;  // m-frags per wave (8 or 4)
  __shared__ __align__(16) unsigned short LDS[2][(BM_ + 256) * 64];
  const int tid = threadIdx.x;
  const int lane = tid & 63, w = tid >> 6;
  const int wm2 = w >> 2, wn4 = w & 3;
  const int l15 = lane & 15, l4 = lane >> 4;

  // XCD-swizzled, weight-panel-inner (m-inner) linearization; nwg % 8 == 0 always
  const int nM = M / BM_, nN = N >> 8;
  const int nwg = nM * nN;
  int bid = blockIdx.x;
  int wg = (bid & 7) * (nwg >> 3) + (bid >> 3);
  int mb = wg % nM, nb = wg / nM;
  const int m0 = mb * BM_, n0 = nb * 256;

  // staging: thread covers 16B; source col pre-XORed (swizzle both-sides rule)
  const int srow = tid >> 3;
  const int scolb = (tid & 7) * 16;
  const int swst = (srow & 7) << 4;
  const char* aS = (const char*)A + ((size_t)(m0 + srow) * K) * 2 + (scolb ^ swst);
  const char* bS = (const char*)Bt + ((size_t)(n0 + srow) * K) * 2 + (scolb ^ swst);
  const size_t rstep = (size_t)64 * K * 2;  // 64 rows down

  const int kb0 = l4 * 16;          // byte offset of lane's k-chunk
  const int swz = (l15 & 7) << 4;   // row&7 == l15&7 for all frag rows

  const int NT = K >> 6;
  f32x4 acc[MFRAG][4] = {};
  bf16x8 bv[4][2], avA[AP][2], avB[AP][2];

#define STAGEX(tt)                                                          \
  {                                                                         \
    unsigned short* ad = &LDS[(tt) & 1][0] + (size_t)tid * 8;               \
    unsigned short* bd = &LDS[(tt) & 1][BM_ * 64] + (size_t)tid * 8;        \
    size_t ko = (size_t)(tt) * 128;                                         \
    _Pragma("unroll")                                                       \
    for (int j = 0; j < NA; ++j) gload_lds16(aS + ko + j * rstep, ad + j * 4096); \
    _Pragma("unroll")                                                       \
    for (int j = 0; j < 4; ++j) gload_lds16(bS + ko + j * rstep, bd + j * 4096);  \
  }

#define READA(dst, p)                                                       \
  _Pragma("unroll")                                                         \
  for (int mm = 0; mm < AP; ++mm)                                           \
  _Pragma("unroll")                                                         \
    for (int ks = 0; ks < 2; ++ks)                                          \
      dst[mm][ks] = *(const bf16x8*)(ab + (AP * (p) + mm) * 2048 +          \
                                     ((kb0 + 64 * ks) ^ swz));

#define GROUP(src, p)                                                       \
  __builtin_amdgcn_s_setprio(1);                                            \
  _Pragma("unroll")                                                         \
  for (int ks = 0; ks < 2; ++ks)                                            \
  _Pragma("unroll")                                                         \
    for (int mm = 0; mm < AP; ++mm)                                         \
    _Pragma("unroll")                                                       \
      for (int ni = 0; ni < 4; ++ni)                                        \
        acc[AP * (p) + mm][ni] =                                            \
            MFMA16(src[mm][ks], bv[ni][ks], acc[AP * (p) + mm][ni], 0, 0, 0);\
  __builtin_amdgcn_s_setprio(0);

  STAGEX(0)
  STAGEX(1)

  for (int t = 0; t < NT; ++t) {
    if (t < NT - 1) {
      if constexpr (BM_ == 256) asm volatile("s_waitcnt vmcnt(8)" ::: "memory");
      else                      asm volatile("s_waitcnt vmcnt(6)" ::: "memory");
    } else {
      asm volatile("s_waitcnt vmcnt(0)" ::: "memory");
    }
    __builtin_amdgcn_s_barrier();
    __builtin_amdgcn_sched_barrier(0);
    const char* ab = (const char*)&LDS[t & 1][0] +
                     (size_t)(wm2 * (BM_ / 2) + l15) * 128;
    const char* bb = (const char*)&LDS[t & 1][BM_ * 64] +
                     (size_t)(wn4 * 64 + l15) * 128;
#pragma unroll
    for (int ni = 0; ni < 4; ++ni)
#pragma unroll
      for (int ks = 0; ks < 2; ++ks)
        bv[ni][ks] = *(const bf16x8*)(bb + ni * 2048 + ((kb0 + 64 * ks) ^ swz));
    READA(avA, 0)
    READA(avB, 1)
    GROUP(avA, 0)        // compiler waits (counted) on B+avA only
    READA(avA, 2)
    GROUP(avB, 1)
    READA(avB, 3)
    GROUP(avA, 2)
    asm volatile("s_waitcnt lgkmcnt(0)" ::: "memory");
    __builtin_amdgcn_sched_barrier(0);
    __builtin_amdgcn_s_barrier();   // all waves done reading buf[t&1]
    __builtin_amdgcn_sched_barrier(0);
    if (t + 2 < NT) STAGEX(t + 2)   // refill buf[t&1] with tile t+2
    GROUP(avB, 3)                   // overlaps stage issue
  }
#undef STAGEX
#undef READA
#undef GROUP

  // epilogue: C frag layout col = lane&15, row = (lane>>4)*4 + reg
  int rbase = m0 + wm2 * (BM_ / 2) + (l4 << 2);
  int cbase = n0 + wn4 * 64 + l15;
#pragma unroll
  for (int ni = 0; ni < 4; ++ni) {
    int col = cbase + ni * 16;
    float bvv = 0.f;
    if (EPI != EPI_QKV) bvv = bias[col];
    if (EPI == EPI_QKV) {
      int which = col >> 10;
      int c2 = col & 1023;
      int h = c2 >> 6, s = c2 & 63;
#pragma unroll
      for (int mi = 0; mi < MFRAG; ++mi) {
        f32x4 a4 = acc[mi][ni];
        int row0 = rbase + mi * 16;
        int bb2 = row0 >> 10, t0 = row0 & 1023;
        if (which == 2) {
          u16x4 pk;
          pk[0] = f2b(a4[0]); pk[1] = f2b(a4[1]); pk[2] = f2b(a4[2]); pk[3] = f2b(a4[3]);
          *(u16x4*)(ob2 + ((((size_t)bb2 * NH + h) * HS) + s) * SEQ + t0) = pk;
        } else {
          unsigned short* dst = (which == 0) ? ob0 : ob1;
#pragma unroll
          for (int r = 0; r < 4; ++r)
            dst[((((size_t)bb2 * NH) + h) * SEQ + t0 + r) * HS + s] = f2b(a4[r]);
        }
      }
    } else {
#pragma unroll
      for (int mi = 0; mi < MFRAG; ++mi) {
        f32x4 a4 = acc[mi][ni];
#pragma unroll
        for (int r = 0; r < 4; ++r) {
          int rowg = rbase + mi * 16 + r;
          size_t off = (size_t)rowg * N + col;
          float v = a4[r] + bvv;
          if (EPI == EPI_RES) outf[off] = v + res[off];
          else if (EPI == EPI_LOGITS) outf[off] = v;
          else if (EPI == EPI_RELU) ob0[off] = f2b(fmaxf(v, 0.f));
        }
      }
    }
  }
}

// ---------------- MFMA flash attention (swapped-operand, causal) ----------------
__global__ __launch_bounds__(256) void attn_mfma(
    const unsigned short* __restrict__ q, const unsigned short* __restrict__ k,
    const unsigned short* __restrict__ vt, unsigned short* __restrict__ outp) {
  __shared__ __align__(16) unsigned short S[8192];  // Ks[4096] | Vs[4096]; reused as Ol
  unsigned short* Ks = S;
  unsigned short* Vs = S + 4096;
  int qt = blockIdx.x, bh = blockIdx.y;
  int tid = threadIdx.x;
  int lane = tid & 63, w = tid >> 6;
  int l15 = lane & 15, l4 = lane >> 4;

  const unsigned short* qb = q + (size_t)bh * SEQ * HS;
  const unsigned short* kb = k + (size_t)bh * SEQ * HS;
  const unsigned short* vb = vt + (size_t)bh * HS * SEQ;

  int q_l = w * 16 + l15;
  int q_g = qt * 64 + q_l;
  bf16x8 qf[2];
  qf[0] = *(const bf16x8*)(qb + (size_t)q_g * HS + l4 * 8);
  qf[1] = *(const bf16x8*)(qb + (size_t)q_g * HS + l4 * 8 + 32);

  int i0 = tid, i1 = tid + 256;
  int kOff0 = (i0 >> 7) * 16 * HS + (i0 & 15) * HS + ((i0 >> 4) & 7) * 8;
  int kOff1 = (i1 >> 7) * 16 * HS + (i1 & 15) * HS + ((i1 >> 4) & 7) * 8;
  int vOff0 = ((i0 >> 7) * 16 + (i0 & 15)) * SEQ + ((i0 >> 4) & 7) * 8;
  int vOff1 = ((i1 >> 7) * 16 + (i1 & 15)) * SEQ + ((i1 >> 4) & 7) * 8;

  f32x4 o[4] = {};
  float mrun = -1e30f, lrun = 0.f;
  int baseLane = 32 * (l4 & 1) + l15;
  bool hi_t = (l4 >> 1) != 0;

  for (int kt = 0; kt <= qt; ++kt) {
    __syncthreads();
    const unsigned short* ksrc = kb + (size_t)kt * 64 * HS;
    gload_lds16(ksrc + kOff0, Ks + (size_t)i0 * 8);
    gload_lds16(ksrc + kOff1, Ks + (size_t)i1 * 8);
    gload_lds16(vb + vOff0 + kt * 64, Vs + (size_t)i0 * 8);
    gload_lds16(vb + vOff1 + kt * 64, Vs + (size_t)i1 * 8);
    __syncthreads();

    f32x4 s[4];
#pragma unroll
    for (int t = 0; t < 4; ++t) {
      bf16x8 kf0 = *(const bf16x8*)(Ks + ((size_t)(t * 8 + l4) * 16 + l15) * 8);
      bf16x8 kf1 = *(const bf16x8*)(Ks + ((size_t)(t * 8 + l4 + 4) * 16 + l15) * 8);
      s[t] = (f32x4){0.f, 0.f, 0.f, 0.f};
      s[t] = MFMA16(kf0, qf[0], s[t], 0, 0, 0);
      s[t] = MFMA16(kf1, qf[1], s[t], 0, 0, 0);
    }

    bool diag = (kt == qt);
    int keybase = kt * 64 + 4 * l4;
    float mx = -1e30f;
#pragma unroll
    for (int t = 0; t < 4; ++t)
#pragma unroll
      for (int r = 0; r < 4; ++r) {
        float sv = s[t][r] * 0.125f;
        if (diag && (keybase + 16 * t + r) > q_g) sv = -1e30f;
        s[t][r] = sv;
        mx = fmaxf(mx, sv);
      }
    mx = fmaxf(mx, __shfl_xor(mx, 16, 64));
    mx = fmaxf(mx, __shfl_xor(mx, 32, 64));
    float mnew = fmaxf(mrun, mx);
    float sc = __expf(mrun - mnew);
    float ps = 0.f;
    float p[4][4];
#pragma unroll
    for (int t = 0; t < 4; ++t)
#pragma unroll
      for (int r = 0; r < 4; ++r) {
        float e = __expf(s[t][r] - mnew);
        p[t][r] = e;
        ps += e;
      }
    ps += __shfl_xor(ps, 16, 64);
    ps += __shfl_xor(ps, 32, 64);
    lrun = lrun * sc + ps;
    mrun = mnew;
#pragma unroll
    for (int t2 = 0; t2 < 4; ++t2)
#pragma unroll
      for (int r = 0; r < 4; ++r) o[t2][r] *= sc;

    int pd[4][2];
#pragma unroll
    for (int t = 0; t < 4; ++t)
#pragma unroll
      for (int h = 0; h < 2; ++h)
        pd[t][h] = (int)f2b(p[t][2 * h]) | ((int)f2b(p[t][2 * h + 1]) << 16);

#pragma unroll
    for (int kk = 0; kk < 2; ++kk) {
      int a0 = __shfl(pd[2 * kk][0], baseLane, 64);
      int b0 = __shfl(pd[2 * kk + 1][0], baseLane, 64);
      int a1 = __shfl(pd[2 * kk][1], baseLane, 64);
      int b1 = __shfl(pd[2 * kk + 1][1], baseLane, 64);
      int a2 = __shfl(pd[2 * kk][0], baseLane + 16, 64);
      int b2 = __shfl(pd[2 * kk + 1][0], baseLane + 16, 64);
      int a3 = __shfl(pd[2 * kk][1], baseLane + 16, 64);
      int b3 = __shfl(pd[2 * kk + 1][1], baseLane + 16, 64);
      union { int4 i4; bf16x8 v; } yu;
      yu.i4.x = hi_t ? b0 : a0;
      yu.i4.y = hi_t ? b1 : a1;
      yu.i4.z = hi_t ? b2 : a2;
      yu.i4.w = hi_t ? b3 : a3;
#pragma unroll
      for (int t2 = 0; t2 < 4; ++t2) {
        bf16x8 vf = *(const bf16x8*)(Vs + ((size_t)(t2 * 8 + l4 + 4 * kk) * 16 + l15) * 8);
        o[t2] = MFMA16(vf, yu.v, o[t2], 0, 0, 0);
      }
    }
  }

  __syncthreads();
  float inv = 1.0f / lrun;
  unsigned short* Ol = S;
#pragma unroll
  for (int t2 = 0; t2 < 4; ++t2) {
    u16x4 p4;
#pragma unroll
    for (int r = 0; r < 4; ++r) p4[r] = f2b(o[t2][r] * inv);
    *(u16x4*)(Ol + (size_t)q_l * 72 + 16 * t2 + 4 * l4) = p4;
  }
  __syncthreads();
  int row = tid >> 2, hs0 = (tid & 3) * 16;
  int bidx = bh >> 4, h = bh & 15;
  size_t gbase = ((size_t)bidx * SEQ + qt * 64 + row) * DMODEL + h * HS + hs0;
  u16x8 r0 = *(const u16x8*)(Ol + (size_t)row * 72 + hs0);
  u16x8 r1 = *(const u16x8*)(Ol + (size_t)row * 72 + hs0 + 8);
  *(u16x8*)(outp + gbase) = r0;
  *(u16x8*)(outp + gbase + 8) = r1;
}

extern "C" void kernel_launch(void* const* d_in, const int* in_sizes, int n_in,
                              void* d_out, int out_size, void* d_ws, size_t ws_size,
                              hipStream_t stream) {
  const int*   tokens  = (const int*)d_in[0];
  const float* tok_emb = (const float*)d_in[1];
  const float* pos_emb = (const float*)d_in[2];
  const float* Wq      = (const float*)d_in[3];
  const float* Wk      = (const float*)d_in[4];
  const float* Wv      = (const float*)d_in[5];
  const float* Wo      = (const float*)d_in[6];
  const float* bo      = (const float*)d_in[7];
  const float* ln1_g   = (const float*)d_in[8];
  const float* ln1_b   = (const float*)d_in[9];
  const float* ln2_g   = (const float*)d_in[10];
  const float* ln2_b   = (const float*)d_in[11];
  const float* W1      = (const float*)d_in[12];
  const float* b1      = (const float*)d_in[13];
  const float* W2      = (const float*)d_in[14];
  const float* b2      = (const float*)d_in[15];
  const float* lnf_g   = (const float*)d_in[16];
  const float* lnf_b   = (const float*)d_in[17];
  const float* W_out   = (const float*)d_in[18];
  const float* b_out   = (const float*)d_in[19];
  float* logits = (float*)d_out;

  char* p = (char*)d_ws;
  float* x = (float*)p;            p += (size_t)ROWS * DMODEL * 4;
  unsigned short* hb = (unsigned short*)p;  p += (size_t)ROWS * DMODEL * 2;
  unsigned short* qb = (unsigned short*)p;  p += (size_t)ROWS * DMODEL * 2;
  unsigned short* kb = (unsigned short*)p;  p += (size_t)ROWS * DMODEL * 2;
  unsigned short* vtb = (unsigned short*)p; p += (size_t)ROWS * DMODEL * 2;
  unsigned short* att = (unsigned short*)p; p += (size_t)ROWS * DMODEL * 2;
  unsigned short* hid = (unsigned short*)p; p += (size_t)ROWS * 4 * DMODEL * 2;
  unsigned short* qkvt = (unsigned short*)p; p += (size_t)NL * 3 * DMODEL * DMODEL * 2;
  unsigned short* wot = (unsigned short*)p;  p += (size_t)NL * DMODEL * DMODEL * 2;
  unsigned short* w1t = (unsigned short*)p;  p += (size_t)NL * 4 * DMODEL * DMODEL * 2;
  unsigned short* w2t = (unsigned short*)p;  p += (size_t)NL * 4 * DMODEL * DMODEL * 2;
  unsigned short* woutt = (unsigned short*)p; p += (size_t)VOCAB * DMODEL * 2;

  transconv<<<dim3(32, 32, NL), 256, 0, stream>>>(Wo, wot, DMODEL, DMODEL);
  transconv<<<dim3(128, 32, NL), 256, 0, stream>>>(W1, w1t, DMODEL, 4 * DMODEL);
  transconv<<<dim3(32, 128, NL), 256, 0, stream>>>(W2, w2t, 4 * DMODEL, DMODEL);
  transconv<<<dim3(1000, 32, 1), 256, 0, stream>>>(W_out, woutt, DMODEL, VOCAB);
  qkv_transconv<<<dim3(2, 32, NL * 48), 256, 0, stream>>>(Wq, Wk, Wv, qkvt);

  embed_kernel<<<ROWS, 256, 0, stream>>>(tokens, tok_emb, pos_emb, x);

  for (int l = 0; l < NL; ++l) {
    ln_kernel<<<ROWS, 256, 0, stream>>>(x, hb, ln1_g + l * DMODEL, ln1_b + l * DMODEL);
    mmX<EPI_QKV, 256><<<192, 512, 0, stream>>>(
        hb, qkvt + (size_t)l * 3 * DMODEL * DMODEL, nullptr, nullptr,
        nullptr, qb, kb, vtb, ROWS, 3 * DMODEL, DMODEL);
    attn_mfma<<<dim3(SEQ / 64, NB * NH), 256, 0, stream>>>(qb, kb, vtb, att);
    mmX<EPI_RES, 128><<<128, 512, 0, stream>>>(
        att, wot + (size_t)l * DMODEL * DMODEL, bo + l * DMODEL, x,
        x, nullptr, nullptr, nullptr, ROWS, DMODEL, DMODEL);
    ln_kernel<<<ROWS, 256, 0, stream>>>(x, hb, ln2_g + l * DMODEL, ln2_b + l * DMODEL);
    mmX<EPI_RELU, 256><<<256, 512, 0, stream>>>(
        hb, w1t + (size_t)l * 4 * DMODEL * DMODEL, b1 + (size_t)l * 4 * DMODEL, nullptr,
        nullptr, hid, nullptr, nullptr, ROWS, 4 * DMODEL, DMODEL);
    mmX<EPI_RES, 128><<<128, 512, 0, stream>>>(
        hid, w2t + (size_t)l * 4 * DMODEL * DMODEL, b2 + l * DMODEL, x,
        x, nullptr, nullptr, nullptr, ROWS, DMODEL, 4 * DMODEL);
  }

  ln_kernel<<<ROWS, 256, 0, stream>>>(x, hb, lnf_g, lnf_b);
  mmX<EPI_LOGITS, 256><<<2000, 512, 0, stream>>>(
      hb, woutt, b_out, nullptr, logits, nullptr, nullptr, nullptr,
      ROWS, VOCAB, DMODEL);
}

// Round 8
// 1828.062 us; speedup vs baseline: 8.2770x; 1.0624x over previous
//
#include <hip/hip_runtime.h>
#include <hip/hip_bf16.h>

#define HS 64
#define NH 16
#define DMODEL 1024
#define SEQ 1024
#define NB 4
#define NL 6
#define VOCAB 32000
#define EPS_LN 1e-5f

static constexpr int ROWS = NB * SEQ;  // 4096

typedef float f32x4 __attribute__((ext_vector_type(4)));
typedef short bf16x8 __attribute__((ext_vector_type(8)));
typedef unsigned short u16x8 __attribute__((ext_vector_type(8)));
typedef unsigned short u16x4 __attribute__((ext_vector_type(4)));

__device__ __forceinline__ unsigned short f2b(float f) {
  __hip_bfloat16 h = __float2bfloat16(f);
  return *reinterpret_cast<unsigned short*>(&h);
}
__device__ __forceinline__ void gload_lds16(const void* g, void* l) {
  __builtin_amdgcn_global_load_lds(
      (const __attribute__((address_space(1))) void*)g,
      (__attribute__((address_space(3))) void*)l, 16, 0, 0);
}
#define MFMA16 __builtin_amdgcn_mfma_f32_16x16x32_bf16
#define EXP2F __builtin_amdgcn_exp2f

// ---------------- embedding ----------------
__global__ __launch_bounds__(256) void embed_kernel(
    const int* __restrict__ tokens, const float* __restrict__ tok_emb,
    const float* __restrict__ pos_emb, float* __restrict__ x) {
  int row = blockIdx.x;
  int t = row & (SEQ - 1);
  int tok = tokens[row];
  int d = threadIdx.x * 4;
  float4 te = *(const float4*)(tok_emb + (size_t)tok * DMODEL + d);
  float4 pe = *(const float4*)(pos_emb + (size_t)t * DMODEL + d);
  te.x += pe.x; te.y += pe.y; te.z += pe.z; te.w += pe.w;
  *(float4*)(x + (size_t)row * DMODEL + d) = te;
}

// ---------------- LayerNorm: f32 in -> bf16 out ----------------
__global__ __launch_bounds__(256) void ln_kernel(
    const float* __restrict__ in, unsigned short* __restrict__ outp,
    const float* __restrict__ g, const float* __restrict__ b) {
  int row = blockIdx.x;
  int tid = threadIdx.x;
  const float* xr = in + (size_t)row * DMODEL;
  float4 v4 = *(const float4*)(xr + tid * 4);
  float s = v4.x + v4.y + v4.z + v4.w;
  float s2 = v4.x * v4.x + v4.y * v4.y + v4.z * v4.z + v4.w * v4.w;
#pragma unroll
  for (int off = 32; off > 0; off >>= 1) {
    s  += __shfl_down(s, off, 64);
    s2 += __shfl_down(s2, off, 64);
  }
  __shared__ float red[8];
  __shared__ float stats[2];
  int wv = tid >> 6, lane = tid & 63;
  if (lane == 0) { red[wv] = s; red[4 + wv] = s2; }
  __syncthreads();
  if (tid == 0) {
    float ts = red[0] + red[1] + red[2] + red[3];
    float ts2 = red[4] + red[5] + red[6] + red[7];
    float mu = ts * (1.0f / DMODEL);
    float var = ts2 * (1.0f / DMODEL) - mu * mu;
    stats[0] = mu;
    stats[1] = rsqrtf(var + EPS_LN);
  }
  __syncthreads();
  float mu = stats[0], rstd = stats[1];
  float4 g4 = *(const float4*)(g + tid * 4);
  float4 b4 = *(const float4*)(b + tid * 4);
  u16x4 o;
  o[0] = f2b((v4.x - mu) * rstd * g4.x + b4.x);
  o[1] = f2b((v4.y - mu) * rstd * g4.y + b4.y);
  o[2] = f2b((v4.z - mu) * rstd * g4.z + b4.z);
  o[3] = f2b((v4.w - mu) * rstd * g4.w + b4.w);
  *(u16x4*)(outp + (size_t)row * DMODEL + tid * 4) = o;
}

// ---------------- transpose-convert: f32 [K][N] -> bf16 [N][K], 64k x 32n tiles ----------------
__global__ __launch_bounds__(256) void transconv(
    const float* __restrict__ in, unsigned short* __restrict__ outp, int K, int N) {
  __shared__ float tile[64][33];
  size_t zoff = (size_t)blockIdx.z * K * N;
  in += zoff;
  outp += zoff;
  int n0 = blockIdx.x * 32, k0 = blockIdx.y * 64;
  int tx = threadIdx.x & 31, ty = threadIdx.x >> 5;
#pragma unroll
  for (int i = 0; i < 8; ++i)
    tile[ty + i * 8][tx] = in[(size_t)(k0 + ty + i * 8) * N + n0 + tx];
  __syncthreads();
  int n = threadIdx.x >> 3;
  int kq = (threadIdx.x & 7) * 8;
  u16x8 o8;
#pragma unroll
  for (int j = 0; j < 8; ++j) o8[j] = f2b(tile[kq + j][n]);
  *(u16x8*)(outp + (size_t)(n0 + n) * K + k0 + kq) = o8;
}

// ---------------- QKV weight transpose-convert (64d x 32s tiles) ----------------
__global__ __launch_bounds__(256) void qkv_transconv(
    const float* __restrict__ Wq, const float* __restrict__ Wk,
    const float* __restrict__ Wv, unsigned short* __restrict__ outp) {
  __shared__ float tile[64][33];
  int z = blockIdx.z;            // l*48 + which*16 + h
  int l = z / 48;
  int r = z % 48;
  int which = r >> 4, h = r & 15;
  const float* W = (which == 0 ? Wq : which == 1 ? Wk : Wv) +
                   ((size_t)l * NH + h) * DMODEL * HS;
  int s0 = blockIdx.x * 32, d0 = blockIdx.y * 64;
  int tx = threadIdx.x & 31, ty = threadIdx.x >> 5;
#pragma unroll
  for (int i = 0; i < 8; ++i)
    tile[ty + i * 8][tx] = W[(size_t)(d0 + ty + i * 8) * HS + s0 + tx];
  __syncthreads();
  unsigned short* ob = outp + ((size_t)l * 3072 + which * 1024 + h * 64) * DMODEL;
  int n = threadIdx.x >> 3;
  int kq = (threadIdx.x & 7) * 8;
  u16x8 o8;
#pragma unroll
  for (int j = 0; j < 8; ++j) o8[j] = f2b(tile[kq + j][n]);
  *(u16x8*)(ob + (size_t)(s0 + n) * DMODEL + d0 + kq) = o8;
}

// ---------------- bf16 MFMA GEMM, BM_ x 256 tile, BK=64, phase-pipelined ----------------
#define EPI_LOGITS 0
#define EPI_RES 1
#define EPI_RELU 2
#define EPI_QKV 3

template <int EPI, int BM_>
__global__ __launch_bounds__(512, 2) void mmX(
    const unsigned short* __restrict__ A, const unsigned short* __restrict__ Bt,
    const float* __restrict__ bias, const float* __restrict__ res,
    float* __restrict__ outf, unsigned short* __restrict__ ob0,
    unsigned short* __restrict__ ob1, unsigned short* __restrict__ ob2,
    int M, int N, int K) {
  constexpr int NA = BM_ / 64;
  constexpr int AP = BM_ / 128;
  constexpr int MFRAG = BM_ / 32;
  __shared__ __align__(16) unsigned short LDS[2][(BM_ + 256) * 64];
  const int tid = threadIdx.x;
  const int lane = tid & 63, w = tid >> 6;
  const int wm2 = w >> 2, wn4 = w & 3;
  const int l15 = lane & 15, l4 = lane >> 4;

  const int nM = M / BM_, nN = N >> 8;
  const int nwg = nM * nN;
  int bid = blockIdx.x;
  int wg = (bid & 7) * (nwg >> 3) + (bid >> 3);
  int mb = wg % nM, nb = wg / nM;
  const int m0 = mb * BM_, n0 = nb * 256;

  const int srow = tid >> 3;
  const int scolb = (tid & 7) * 16;
  const int swst = (srow & 7) << 4;
  const char* aS = (const char*)A + ((size_t)(m0 + srow) * K) * 2 + (scolb ^ swst);
  const char* bS = (const char*)Bt + ((size_t)(n0 + srow) * K) * 2 + (scolb ^ swst);
  const size_t rstep = (size_t)64 * K * 2;

  const int kb0 = l4 * 16;
  const int swz = (l15 & 7) << 4;

  const int NT = K >> 6;
  f32x4 acc[MFRAG][4] = {};
  bf16x8 bv[4][2], avA[AP][2], avB[AP][2];

#define STAGEX(tt)                                                          \
  {                                                                         \
    unsigned short* ad = &LDS[(tt) & 1][0] + (size_t)tid * 8;               \
    unsigned short* bd = &LDS[(tt) & 1][BM_ * 64] + (size_t)tid * 8;        \
    size_t ko = (size_t)(tt) * 128;                                         \
    _Pragma("unroll")                                                       \
    for (int j = 0; j < NA; ++j) gload_lds16(aS + ko + j * rstep, ad + j * 4096); \
    _Pragma("unroll")                                                       \
    for (int j = 0; j < 4; ++j) gload_lds16(bS + ko + j * rstep, bd + j * 4096);  \
  }

#define READA(dst, p)                                                       \
  _Pragma("unroll")                                                         \
  for (int mm = 0; mm < AP; ++mm)                                           \
  _Pragma("unroll")                                                         \
    for (int ks = 0; ks < 2; ++ks)                                          \
      dst[mm][ks] = *(const bf16x8*)(ab + (AP * (p) + mm) * 2048 +          \
                                     ((kb0 + 64 * ks) ^ swz));

#define GROUP(src, p)                                                       \
  __builtin_amdgcn_s_setprio(1);                                            \
  _Pragma("unroll")                                                         \
  for (int ks = 0; ks < 2; ++ks)                                            \
  _Pragma("unroll")                                                         \
    for (int mm = 0; mm < AP; ++mm)                                         \
    _Pragma("unroll")                                                       \
      for (int ni = 0; ni < 4; ++ni)                                        \
        acc[AP * (p) + mm][ni] =                                            \
            MFMA16(src[mm][ks], bv[ni][ks], acc[AP * (p) + mm][ni], 0, 0, 0);\
  __builtin_amdgcn_s_setprio(0);

  STAGEX(0)
  STAGEX(1)

  for (int t = 0; t < NT; ++t) {
    if (t < NT - 1) {
      if constexpr (BM_ == 256) asm volatile("s_waitcnt vmcnt(8)" ::: "memory");
      else                      asm volatile("s_waitcnt vmcnt(6)" ::: "memory");
    } else {
      asm volatile("s_waitcnt vmcnt(0)" ::: "memory");
    }
    __builtin_amdgcn_s_barrier();
    __builtin_amdgcn_sched_barrier(0);
    const char* ab = (const char*)&LDS[t & 1][0] +
                     (size_t)(wm2 * (BM_ / 2) + l15) * 128;
    const char* bb = (const char*)&LDS[t & 1][BM_ * 64] +
                     (size_t)(wn4 * 64 + l15) * 128;
#pragma unroll
    for (int ni = 0; ni < 4; ++ni)
#pragma unroll
      for (int ks = 0; ks < 2; ++ks)
        bv[ni][ks] = *(const bf16x8*)(bb + ni * 2048 + ((kb0 + 64 * ks) ^ swz));
    READA(avA, 0)
    READA(avB, 1)
    GROUP(avA, 0)
    READA(avA, 2)
    GROUP(avB, 1)
    READA(avB, 3)
    GROUP(avA, 2)
    asm volatile("s_waitcnt lgkmcnt(0)" ::: "memory");
    __builtin_amdgcn_sched_barrier(0);
    __builtin_amdgcn_s_barrier();
    __builtin_amdgcn_sched_barrier(0);
    if (t + 2 < NT) STAGEX(t + 2)
    GROUP(avB, 3)
  }
#undef STAGEX
#undef READA
#undef GROUP

  int rbase = m0 + wm2 * (BM_ / 2) + (l4 << 2);
  int cbase = n0 + wn4 * 64 + l15;

  if constexpr (EPI == EPI_LOGITS) {
    // stage C through LDS -> full-row coalesced nontemporal f32x4 stores
    float* fl = (float*)&LDS[0][0];  // 128 KB = 128 rows x 256 f32
#pragma unroll
    for (int half = 0; half < 2; ++half) {
      __syncthreads();
      if (wm2 == half) {
#pragma unroll
        for (int ni = 0; ni < 4; ++ni) {
          float bvv = bias[cbase + ni * 16];
          int cl = wn4 * 64 + l15 + ni * 16;
#pragma unroll
          for (int mi = 0; mi < MFRAG; ++mi) {
            int rl = mi * 16 + (l4 << 2);
#pragma unroll
            for (int r = 0; r < 4; ++r)
              fl[(rl + r) * 256 + cl] = acc[mi][ni][r] + bvv;
          }
        }
      }
      __syncthreads();
#pragma unroll
      for (int j = 0; j < 16; ++j) {
        int idx = j * 512 + tid;
        int rl = idx >> 6;
        int cc = (idx & 63) << 2;
        f32x4 v4 = *(const f32x4*)&fl[rl * 256 + cc];
        float* gp = outf + (size_t)(m0 + half * 128 + rl) * N + n0 + cc;
        __builtin_nontemporal_store(v4, (f32x4*)gp);
      }
    }
  } else {
#pragma unroll
    for (int ni = 0; ni < 4; ++ni) {
      int col = cbase + ni * 16;
      float bvv = 0.f;
      if (EPI != EPI_QKV) bvv = bias[col];
      if (EPI == EPI_QKV) {
        int which = col >> 10;
        int c2 = col & 1023;
        int h = c2 >> 6, s = c2 & 63;
#pragma unroll
        for (int mi = 0; mi < MFRAG; ++mi) {
          f32x4 a4 = acc[mi][ni];
          int row0 = rbase + mi * 16;
          int bb2 = row0 >> 10, t0 = row0 & 1023;
          if (which == 2) {
            u16x4 pk;
            pk[0] = f2b(a4[0]); pk[1] = f2b(a4[1]); pk[2] = f2b(a4[2]); pk[3] = f2b(a4[3]);
            *(u16x4*)(ob2 + ((((size_t)bb2 * NH + h) * HS) + s) * SEQ + t0) = pk;
          } else {
            unsigned short* dst = (which == 0) ? ob0 : ob1;
#pragma unroll
            for (int r = 0; r < 4; ++r)
              dst[((((size_t)bb2 * NH) + h) * SEQ + t0 + r) * HS + s] = f2b(a4[r]);
          }
        }
      } else {
#pragma unroll
        for (int mi = 0; mi < MFRAG; ++mi) {
          f32x4 a4 = acc[mi][ni];
#pragma unroll
          for (int r = 0; r < 4; ++r) {
            int rowg = rbase + mi * 16 + r;
            size_t off = (size_t)rowg * N + col;
            float v = a4[r] + bvv;
            if (EPI == EPI_RES) outf[off] = v + res[off];
            else if (EPI == EPI_RELU) ob0[off] = f2b(fmaxf(v, 0.f));
          }
        }
      }
    }
  }
}

// ---------------- MFMA flash attention (swapped-operand, causal, dbuf) ----------------
__global__ __launch_bounds__(256) void attn_mfma(
    const unsigned short* __restrict__ q, const unsigned short* __restrict__ k,
    const unsigned short* __restrict__ vt, unsigned short* __restrict__ outp) {
  __shared__ __align__(16) unsigned short S[16384];  // K[2][4096] | V[2][4096]
  unsigned short* Ks = S;
  unsigned short* Vs = S + 8192;
  int qt = blockIdx.x, bh = blockIdx.y;
  int tid = threadIdx.x;
  int lane = tid & 63, w = tid >> 6;
  int l15 = lane & 15, l4 = lane >> 4;

  const unsigned short* qb = q + (size_t)bh * SEQ * HS;
  const unsigned short* kb = k + (size_t)bh * SEQ * HS;
  const unsigned short* vb = vt + (size_t)bh * HS * SEQ;

  int q_l = w * 16 + l15;
  int q_g = qt * 64 + q_l;
  bf16x8 qf[2];
  qf[0] = *(const bf16x8*)(qb + (size_t)q_g * HS + l4 * 8);
  qf[1] = *(const bf16x8*)(qb + (size_t)q_g * HS + l4 * 8 + 32);

  int i0 = tid, i1 = tid + 256;
  int kOff0 = (i0 >> 7) * 16 * HS + (i0 & 15) * HS + ((i0 >> 4) & 7) * 8;
  int kOff1 = (i1 >> 7) * 16 * HS + (i1 & 15) * HS + ((i1 >> 4) & 7) * 8;
  int vOff0 = ((i0 >> 7) * 16 + (i0 & 15)) * SEQ + ((i0 >> 4) & 7) * 8;
  int vOff1 = ((i1 >> 7) * 16 + (i1 & 15)) * SEQ + ((i1 >> 4) & 7) * 8;

#define ASTAGE(tt)                                                           \
  {                                                                          \
    int bsel = ((tt) & 1) * 4096;                                            \
    const unsigned short* ksrc = kb + (size_t)(tt) * 64 * HS;                \
    gload_lds16(ksrc + kOff0, Ks + bsel + (size_t)i0 * 8);                   \
    gload_lds16(ksrc + kOff1, Ks + bsel + (size_t)i1 * 8);                   \
    gload_lds16(vb + vOff0 + (tt) * 64, Vs + bsel + (size_t)i0 * 8);         \
    gload_lds16(vb + vOff1 + (tt) * 64, Vs + bsel + (size_t)i1 * 8);         \
  }

  f32x4 o[4] = {};
  float mrun = -3e38f, lrun = 0.f;
  int baseLane = 32 * (l4 & 1) + l15;
  bool hi_t = (l4 >> 1) != 0;
  const float CSC = 0.125f * 1.44269504f;  // fold 1/sqrt(HS) into exp2
  const float THR = 8.0f / CSC;            // defer-max threshold (raw-score domain)

  ASTAGE(0)

  for (int kt = 0; kt <= qt; ++kt) {
    asm volatile("s_waitcnt vmcnt(0)" ::: "memory");
    __builtin_amdgcn_s_barrier();
    __builtin_amdgcn_sched_barrier(0);
    if (kt < qt) ASTAGE(kt + 1)   // in flight under compute
    const unsigned short* Kb = Ks + (kt & 1) * 4096;
    const unsigned short* Vb = Vs + (kt & 1) * 4096;

    f32x4 s[4];
#pragma unroll
    for (int t = 0; t < 4; ++t) {
      bf16x8 kf0 = *(const bf16x8*)(Kb + ((size_t)(t * 8 + l4) * 16 + l15) * 8);
      bf16x8 kf1 = *(const bf16x8*)(Kb + ((size_t)(t * 8 + l4 + 4) * 16 + l15) * 8);
      s[t] = (f32x4){0.f, 0.f, 0.f, 0.f};
      s[t] = MFMA16(kf0, qf[0], s[t], 0, 0, 0);
      s[t] = MFMA16(kf1, qf[1], s[t], 0, 0, 0);
    }

    if (kt == qt) {  // diag tile only: causal mask (raw-score domain)
      int keybase = kt * 64 + 4 * l4;
#pragma unroll
      for (int t = 0; t < 4; ++t)
#pragma unroll
        for (int r = 0; r < 4; ++r)
          if (keybase + 16 * t + r > q_g) s[t][r] = -3e38f;
    }
    float mx = -3e38f;
#pragma unroll
    for (int t = 0; t < 4; ++t)
#pragma unroll
      for (int r = 0; r < 4; ++r) mx = fmaxf(mx, s[t][r]);
    mx = fmaxf(mx, __shfl_xor(mx, 16, 64));
    mx = fmaxf(mx, __shfl_xor(mx, 32, 64));
    if (!__all(mx - mrun <= THR)) {  // T13 defer-max
      float mnew = fmaxf(mrun, mx);
      float sc = EXP2F((mrun - mnew) * CSC);
      lrun *= sc;
#pragma unroll
      for (int t2 = 0; t2 < 4; ++t2)
#pragma unroll
        for (int r = 0; r < 4; ++r) o[t2][r] *= sc;
      mrun = mnew;
    }
    float mc = mrun * CSC;
    float ps = 0.f;
    float p[4][4];
#pragma unroll
    for (int t = 0; t < 4; ++t)
#pragma unroll
      for (int r = 0; r < 4; ++r) {
        float e = EXP2F(__builtin_fmaf(s[t][r], CSC, -mc));
        p[t][r] = e;
        ps += e;
      }
    ps += __shfl_xor(ps, 16, 64);
    ps += __shfl_xor(ps, 32, 64);
    lrun += ps;

    int pd[4][2];
#pragma unroll
    for (int t = 0; t < 4; ++t)
#pragma unroll
      for (int h = 0; h < 2; ++h)
        pd[t][h] = (int)f2b(p[t][2 * h]) | ((int)f2b(p[t][2 * h + 1]) << 16);

#pragma unroll
    for (int kk = 0; kk < 2; ++kk) {
      int a0 = __shfl(pd[2 * kk][0], baseLane, 64);
      int b0 = __shfl(pd[2 * kk + 1][0], baseLane, 64);
      int a1 = __shfl(pd[2 * kk][1], baseLane, 64);
      int b1 = __shfl(pd[2 * kk + 1][1], baseLane, 64);
      int a2 = __shfl(pd[2 * kk][0], baseLane + 16, 64);
      int b2 = __shfl(pd[2 * kk + 1][0], baseLane + 16, 64);
      int a3 = __shfl(pd[2 * kk][1], baseLane + 16, 64);
      int b3 = __shfl(pd[2 * kk + 1][1], baseLane + 16, 64);
      union { int4 i4; bf16x8 v; } yu;
      yu.i4.x = hi_t ? b0 : a0;
      yu.i4.y = hi_t ? b1 : a1;
      yu.i4.z = hi_t ? b2 : a2;
      yu.i4.w = hi_t ? b3 : a3;
#pragma unroll
      for (int t2 = 0; t2 < 4; ++t2) {
        bf16x8 vf = *(const bf16x8*)(Vb + ((size_t)(t2 * 8 + l4 + 4 * kk) * 16 + l15) * 8);
        o[t2] = MFMA16(vf, yu.v, o[t2], 0, 0, 0);
      }
    }
  }
#undef ASTAGE

  __syncthreads();
  float inv = 1.0f / lrun;
  unsigned short* Ol = S;
#pragma unroll
  for (int t2 = 0; t2 < 4; ++t2) {
    u16x4 p4;
#pragma unroll
    for (int r = 0; r < 4; ++r) p4[r] = f2b(o[t2][r] * inv);
    *(u16x4*)(Ol + (size_t)q_l * 72 + 16 * t2 + 4 * l4) = p4;
  }
  __syncthreads();
  int row = tid >> 2, hs0 = (tid & 3) * 16;
  int bidx = bh >> 4, h = bh & 15;
  size_t gbase = ((size_t)bidx * SEQ + qt * 64 + row) * DMODEL + h * HS + hs0;
  u16x8 r0 = *(const u16x8*)(Ol + (size_t)row * 72 + hs0);
  u16x8 r1 = *(const u16x8*)(Ol + (size_t)row * 72 + hs0 + 8);
  *(u16x8*)(outp + gbase) = r0;
  *(u16x8*)(outp + gbase + 8) = r1;
}

extern "C" void kernel_launch(void* const* d_in, const int* in_sizes, int n_in,
                              void* d_out, int out_size, void* d_ws, size_t ws_size,
                              hipStream_t stream) {
  const int*   tokens  = (const int*)d_in[0];
  const float* tok_emb = (const float*)d_in[1];
  const float* pos_emb = (const float*)d_in[2];
  const float* Wq      = (const float*)d_in[3];
  const float* Wk      = (const float*)d_in[4];
  const float* Wv      = (const float*)d_in[5];
  const float* Wo      = (const float*)d_in[6];
  const float* bo      = (const float*)d_in[7];
  const float* ln1_g   = (const float*)d_in[8];
  const float* ln1_b   = (const float*)d_in[9];
  const float* ln2_g   = (const float*)d_in[10];
  const float* ln2_b   = (const float*)d_in[11];
  const float* W1      = (const float*)d_in[12];
  const float* b1      = (const float*)d_in[13];
  const float* W2      = (const float*)d_in[14];
  const float* b2      = (const float*)d_in[15];
  const float* lnf_g   = (const float*)d_in[16];
  const float* lnf_b   = (const float*)d_in[17];
  const float* W_out   = (const float*)d_in[18];
  const float* b_out   = (const float*)d_in[19];
  float* logits = (float*)d_out;

  char* p = (char*)d_ws;
  float* x = (float*)p;            p += (size_t)ROWS * DMODEL * 4;
  unsigned short* hb = (unsigned short*)p;  p += (size_t)ROWS * DMODEL * 2;
  unsigned short* qb = (unsigned short*)p;  p += (size_t)ROWS * DMODEL * 2;
  unsigned short* kb = (unsigned short*)p;  p += (size_t)ROWS * DMODEL * 2;
  unsigned short* vtb = (unsigned short*)p; p += (size_t)ROWS * DMODEL * 2;
  unsigned short* att = (unsigned short*)p; p += (size_t)ROWS * DMODEL * 2;
  unsigned short* hid = (unsigned short*)p; p += (size_t)ROWS * 4 * DMODEL * 2;
  unsigned short* qkvt = (unsigned short*)p; p += (size_t)NL * 3 * DMODEL * DMODEL * 2;
  unsigned short* wot = (unsigned short*)p;  p += (size_t)NL * DMODEL * DMODEL * 2;
  unsigned short* w1t = (unsigned short*)p;  p += (size_t)NL * 4 * DMODEL * DMODEL * 2;
  unsigned short* w2t = (unsigned short*)p;  p += (size_t)NL * 4 * DMODEL * DMODEL * 2;
  unsigned short* woutt = (unsigned short*)p; p += (size_t)VOCAB * DMODEL * 2;

  transconv<<<dim3(32, 16, NL), 256, 0, stream>>>(Wo, wot, DMODEL, DMODEL);
  transconv<<<dim3(128, 16, NL), 256, 0, stream>>>(W1, w1t, DMODEL, 4 * DMODEL);
  transconv<<<dim3(32, 64, NL), 256, 0, stream>>>(W2, w2t, 4 * DMODEL, DMODEL);
  transconv<<<dim3(1000, 16, 1), 256, 0, stream>>>(W_out, woutt, DMODEL, VOCAB);
  qkv_transconv<<<dim3(2, 16, NL * 48), 256, 0, stream>>>(Wq, Wk, Wv, qkvt);

  embed_kernel<<<ROWS, 256, 0, stream>>>(tokens, tok_emb, pos_emb, x);

  for (int l = 0; l < NL; ++l) {
    ln_kernel<<<ROWS, 256, 0, stream>>>(x, hb, ln1_g + l * DMODEL, ln1_b + l * DMODEL);
    mmX<EPI_QKV, 256><<<192, 512, 0, stream>>>(
        hb, qkvt + (size_t)l * 3 * DMODEL * DMODEL, nullptr, nullptr,
        nullptr, qb, kb, vtb, ROWS, 3 * DMODEL, DMODEL);
    attn_mfma<<<dim3(SEQ / 64, NB * NH), 256, 0, stream>>>(qb, kb, vtb, att);
    mmX<EPI_RES, 128><<<128, 512, 0, stream>>>(
        att, wot + (size_t)l * DMODEL * DMODEL, bo + l * DMODEL, x,
        x, nullptr, nullptr, nullptr, ROWS, DMODEL, DMODEL);
    ln_kernel<<<ROWS, 256, 0, stream>>>(x, hb, ln2_g + l * DMODEL, ln2_b + l * DMODEL);
    mmX<EPI_RELU, 256><<<256, 512, 0, stream>>>(
        hb, w1t + (size_t)l * 4 * DMODEL * DMODEL, b1 + (size_t)l * 4 * DMODEL, nullptr,
        nullptr, hid, nullptr, nullptr, ROWS, 4 * DMODEL, DMODEL);
    mmX<EPI_RES, 128><<<128, 512, 0, stream>>>(
        hid, w2t + (size_t)l * 4 * DMODEL * DMODEL, b2 + l * DMODEL, x,
        x, nullptr, nullptr, nullptr, ROWS, DMODEL, 4 * DMODEL);
  }

  ln_kernel<<<ROWS, 256, 0, stream>>>(x, hb, lnf_g, lnf_b);
  mmX<EPI_LOGITS, 256><<<2000, 512, 0, stream>>>(
      hb, woutt, b_out, nullptr, logits, nullptr, nullptr, nullptr,
      ROWS, VOCAB, DMODEL);
}